// Round 1
// baseline (380.908 us; speedup 1.0000x reference)
//
#include <hip/hip_runtime.h>
#include <hip/hip_bf16.h>

// Problem: B=16, S=2048, D=512 fused attention with sum-pool over queries.
// Algebra: out[b] = ((sum_q softmax(X M X^T / ...)[q,:]) @ X_b) @ Wv, M = Wq Wk^T.
// log2(e)/sqrt(D) folded into M so softmax exponentials are native exp2.

#define S_LEN 2048
#define D_DIM 512
#define BATCH 16

typedef short bf16x8 __attribute__((ext_vector_type(8)));
typedef float f32x4 __attribute__((ext_vector_type(4)));

typedef __attribute__((address_space(3))) void lds_void_t;
typedef const __attribute__((address_space(1))) void gbl_void_t;

__device__ __forceinline__ void async_copy16(const void* g, void* l) {
  __builtin_amdgcn_global_load_lds((gbl_void_t*)g, (lds_void_t*)l, 16, 0, 0);
}

__device__ __forceinline__ unsigned short f2bf(float f) {
  unsigned u = __float_as_uint(f);
  u += 0x7fff + ((u >> 16) & 1);   // round-to-nearest-even
  return (unsigned short)(u >> 16);
}

// ---------------- NT GEMM core: C(128x128) = A[M,K] * B[N,K]^T, bf16 in, fp32 acc.
// A,B already offset to block tile origin. K multiple of 32. 256 threads = 4 waves (2x2 of 64x64).
__device__ __forceinline__ void gemm_core_nt(
    const unsigned short* __restrict__ A, long lda,
    const unsigned short* __restrict__ B, long ldb,
    int K, unsigned short* As, unsigned short* Bs, f32x4 acc[4][4])
{
  const int tid  = threadIdx.x;
  const int lane = tid & 63;
  const int w    = tid >> 6;
  const int wm   = w >> 1, wn = w & 1;
  const int r16  = lane & 15;
  const int kq   = lane >> 4;

  // staging chunk ids: 16B chunks, row = j>>2 (4 chunks = 64B = 32 bf16 per row)
  const int j0 = w * 64 + lane;         // chunks 0..255   -> rows 0..63
  const int j1 = (w + 4) * 64 + lane;   // chunks 256..511 -> rows 64..127

  const long a0 = (long)(j0 >> 2) * lda + (j0 & 3) * 8;
  const long a1 = (long)(j1 >> 2) * lda + (j1 & 3) * 8;
  const long b0 = (long)(j0 >> 2) * ldb + (j0 & 3) * 8;
  const long b1 = (long)(j1 >> 2) * ldb + (j1 & 3) * 8;

  for (int k0 = 0; k0 < K; k0 += 32) {
    __syncthreads();   // previous iter's ds_reads complete before overwrite
    async_copy16(A + a0 + k0, (char*)As + (w    ) * 1024);
    async_copy16(A + a1 + k0, (char*)As + (w + 4) * 1024);
    async_copy16(B + b0 + k0, (char*)Bs + (w    ) * 1024);
    async_copy16(B + b1 + k0, (char*)Bs + (w + 4) * 1024);
    __syncthreads();   // compiler drains vmcnt before barrier -> staging visible

    bf16x8 af[4], bg[4];
#pragma unroll
    for (int mt = 0; mt < 4; ++mt)
      af[mt] = *(const bf16x8*)&As[(wm * 64 + mt * 16 + r16) * 32 + kq * 8];
#pragma unroll
    for (int nt = 0; nt < 4; ++nt)
      bg[nt] = *(const bf16x8*)&Bs[(wn * 64 + nt * 16 + r16) * 32 + kq * 8];
#pragma unroll
    for (int mt = 0; mt < 4; ++mt)
#pragma unroll
      for (int nt = 0; nt < 4; ++nt)
        acc[mt][nt] = __builtin_amdgcn_mfma_f32_16x16x32_bf16(af[mt], bg[nt], acc[mt][nt], 0, 0, 0);
  }
}

// ---------------- small utility kernels
__global__ __launch_bounds__(256) void k_zero(float* __restrict__ p, int n) {
  int i = blockIdx.x * 256 + threadIdx.x;
  if (i < n) p[i] = 0.0f;
}

__global__ __launch_bounds__(256) void k_cast(const float* __restrict__ s, unsigned short* __restrict__ d) {
  int i = (blockIdx.x * 256 + threadIdx.x) * 4;  // grids sized exactly
  float4 v = *(const float4*)(s + i);
  ushort4 o;
  o.x = f2bf(v.x); o.y = f2bf(v.y); o.z = f2bf(v.z); o.w = f2bf(v.w);
  *(ushort4*)(d + i) = o;
}

// ---------------- generic NT GEMM with bf16 output (used for Mt and Y)
__global__ __launch_bounds__(256) void k_gemm_bf16out(
    const unsigned short* __restrict__ A, long lda,
    const unsigned short* __restrict__ B, long ldb, int K,
    unsigned short* __restrict__ C, long ldc, float scale)
{
  __shared__ alignas(16) unsigned short As[128 * 32];
  __shared__ alignas(16) unsigned short Bs[128 * 32];
  f32x4 acc[4][4] = {};
  const long am0 = (long)blockIdx.y * 128;
  const long bn0 = (long)blockIdx.x * 128;
  gemm_core_nt(A + am0 * lda, lda, B + bn0 * ldb, ldb, K, As, Bs, acc);

  const int lane = threadIdx.x & 63;
  const int w = threadIdx.x >> 6, wm = w >> 1, wn = w & 1;
  const long row0 = am0 + wm * 64 + (lane >> 4) * 4;
  const long col0 = bn0 + wn * 64 + (lane & 15);
#pragma unroll
  for (int mt = 0; mt < 4; ++mt)
#pragma unroll
    for (int nt = 0; nt < 4; ++nt)
#pragma unroll
      for (int r = 0; r < 4; ++r)
        C[(row0 + mt * 16 + r) * ldc + col0 + nt * 16] = f2bf(acc[mt][nt][r] * scale);
}

// ---------------- pass A: scores tile -> exp2 -> row sums into l[b,q]
__global__ __launch_bounds__(256) void k_passA(
    const unsigned short* __restrict__ Ybf, const unsigned short* __restrict__ Xbf,
    float* __restrict__ lrow)
{
  __shared__ alignas(16) unsigned short As[128 * 32];
  __shared__ alignas(16) unsigned short Bs[128 * 32];
  f32x4 acc[4][4] = {};
  const int b = blockIdx.z;
  const long q0 = (long)blockIdx.y * 128;
  const long n0 = (long)blockIdx.x * 128;
  const unsigned short* A = Ybf + ((long)b * S_LEN + q0) * D_DIM;
  const unsigned short* Bm = Xbf + ((long)b * S_LEN + n0) * D_DIM;
  gemm_core_nt(A, D_DIM, Bm, D_DIM, D_DIM, As, Bs, acc);

  const int lane = threadIdx.x & 63;
  const int w = threadIdx.x >> 6, wm = w >> 1, wn = w & 1;
  (void)wn;
#pragma unroll
  for (int mt = 0; mt < 4; ++mt) {
#pragma unroll
    for (int r = 0; r < 4; ++r) {
      float s = 0.0f;
#pragma unroll
      for (int nt = 0; nt < 4; ++nt) s += __builtin_amdgcn_exp2f(acc[mt][nt][r]);
      s += __shfl_xor(s, 1, 64);
      s += __shfl_xor(s, 2, 64);
      s += __shfl_xor(s, 4, 64);
      s += __shfl_xor(s, 8, 64);
      if ((lane & 15) == 0)
        atomicAdd(&lrow[(long)b * S_LEN + q0 + wm * 64 + mt * 16 + (lane >> 4) * 4 + r], s);
    }
  }
}

// ---------------- pass B: recompute scores, scale rows by 1/l, column sums into w[b,k]
__global__ __launch_bounds__(256) void k_passB(
    const unsigned short* __restrict__ Ybf, const unsigned short* __restrict__ Xbf,
    const float* __restrict__ lrow, float* __restrict__ wcol)
{
  __shared__ alignas(16) unsigned short As[128 * 32];
  __shared__ alignas(16) unsigned short Bs[128 * 32];
  f32x4 acc[4][4] = {};
  const int b = blockIdx.z;
  const long q0 = (long)blockIdx.y * 128;
  const long n0 = (long)blockIdx.x * 128;
  const unsigned short* A = Ybf + ((long)b * S_LEN + q0) * D_DIM;
  const unsigned short* Bm = Xbf + ((long)b * S_LEN + n0) * D_DIM;
  gemm_core_nt(A, D_DIM, Bm, D_DIM, D_DIM, As, Bs, acc);

  const int lane = threadIdx.x & 63;
  const int w = threadIdx.x >> 6, wm = w >> 1, wn = w & 1;
  float csv[4] = {0.0f, 0.0f, 0.0f, 0.0f};
#pragma unroll
  for (int mt = 0; mt < 4; ++mt) {
    const float4 lv = *(const float4*)&lrow[(long)b * S_LEN + q0 + wm * 64 + mt * 16 + (lane >> 4) * 4];
    const float rv[4] = {1.0f / lv.x, 1.0f / lv.y, 1.0f / lv.z, 1.0f / lv.w};
#pragma unroll
    for (int nt = 0; nt < 4; ++nt)
#pragma unroll
      for (int r = 0; r < 4; ++r)
        csv[nt] += __builtin_amdgcn_exp2f(acc[mt][nt][r]) * rv[r];
  }
#pragma unroll
  for (int nt = 0; nt < 4; ++nt) {
    csv[nt] += __shfl_xor(csv[nt], 16, 64);
    csv[nt] += __shfl_xor(csv[nt], 32, 64);
  }
  if (lane < 16) {
#pragma unroll
    for (int nt = 0; nt < 4; ++nt)
      atomicAdd(&wcol[(long)b * S_LEN + n0 + wn * 64 + nt * 16 + lane], csv[nt]);
  }
}

// ---------------- t[b,d] = sum_k w[b,k] * X[b,k,d]  (fp32 X for accuracy)
__global__ __launch_bounds__(256) void k_t(
    const float* __restrict__ X, const float* __restrict__ wcol, float* __restrict__ tvec)
{
  const int b = blockIdx.z;
  const int d = blockIdx.x * 256 + threadIdx.x;
  const int k0 = blockIdx.y * 256;
  const float* Xp = X + ((long)b * S_LEN + k0) * D_DIM + d;
  const float* wp = wcol + (long)b * S_LEN + k0;
  float acc = 0.0f;
#pragma unroll 4
  for (int k = 0; k < 256; ++k) acc += wp[k] * Xp[(long)k * D_DIM];
  atomicAdd(&tvec[b * D_DIM + d], acc);
}

// ---------------- out[b,e] = sum_d t[b,d] * Wv[d,e]  (fp32)
__global__ __launch_bounds__(512) void k_out(
    const float* __restrict__ tvec, const float* __restrict__ Wv, float* __restrict__ out)
{
  __shared__ float tl[128];
  const int b = blockIdx.y;
  const int d0 = blockIdx.x * 128;
  const int e = threadIdx.x;
  if (e < 128) tl[e] = tvec[b * D_DIM + d0 + e];
  __syncthreads();
  float acc = 0.0f;
#pragma unroll 4
  for (int d = 0; d < 128; ++d) acc += tl[d] * Wv[(long)(d0 + d) * D_DIM + e];
  atomicAdd(&out[b * D_DIM + e], acc);
}

extern "C" void kernel_launch(void* const* d_in, const int* in_sizes, int n_in,
                              void* d_out, int out_size, void* d_ws, size_t ws_size,
                              hipStream_t stream) {
  const float* X  = (const float*)d_in[0];  // [16,2048,512]
  const float* Wq = (const float*)d_in[1];  // [512,512]
  const float* Wk = (const float*)d_in[2];
  const float* Wv = (const float*)d_in[3];
  float* out = (float*)d_out;               // [16,512]

  char* ws = (char*)d_ws;
  unsigned short* Xbf = (unsigned short*)(ws);              // 32 MB
  unsigned short* Ybf = (unsigned short*)(ws + 33554432);   // 32 MB
  unsigned short* Mt  = (unsigned short*)(ws + 67108864);   // 512 KB  (Mt[e,d] = M[d,e]*scale)
  unsigned short* Wqb = (unsigned short*)(ws + 67633152);   // 512 KB
  unsigned short* Wkb = (unsigned short*)(ws + 68157440);   // 512 KB
  float* lrow = (float*)(ws + 68681728);                    // 128 KB  l[b,q]
  float* wcol = (float*)(ws + 68812800);                    // 128 KB  w[b,k]
  float* tvec = (float*)(ws + 68943872);                    // 32 KB   t[b,d]

  // zero accumulators (ws/out are poisoned 0xAA before every call)
  k_zero<<<288, 256, 0, stream>>>(lrow, 73728);     // lrow+wcol+tvec contiguous
  k_zero<<<32, 256, 0, stream>>>(out, BATCH * D_DIM);

  // bf16 casts
  k_cast<<<16384, 256, 0, stream>>>(X,  Xbf);   // 16,777,216 elems
  k_cast<<<256,   256, 0, stream>>>(Wq, Wqb);   // 262,144
  k_cast<<<256,   256, 0, stream>>>(Wk, Wkb);

  // Mt[e,d] = (log2(e)/sqrt(512)) * sum_c Wk[e,c] Wq[d,c]
  const float scale = 1.4426950408889634f / 22.627416997969522f;
  k_gemm_bf16out<<<dim3(4, 4), 256, 0, stream>>>(Wkb, 512, Wqb, 512, 512, Mt, 512, scale);

  // Y[i,e] = sum_d Xbf[i,d] * Mt[e,d]   (M = B*S = 32768 rows)
  k_gemm_bf16out<<<dim3(4, 256), 256, 0, stream>>>(Xbf, 512, Mt, 512, 512, Ybf, 512, 1.0f);

  // scores passes: l then w
  k_passA<<<dim3(16, 16, 16), 256, 0, stream>>>(Ybf, Xbf, lrow);
  k_passB<<<dim3(16, 16, 16), 256, 0, stream>>>(Ybf, Xbf, lrow, wcol);

  // t = w @ X (fp32), out = t @ Wv (fp32)
  k_t<<<dim3(2, 8, 16), 256, 0, stream>>>(X, wcol, tvec);
  k_out<<<dim3(4, 16), 512, 0, stream>>>(tvec, Wv, out);
}

// Round 2
// 336.353 us; speedup vs baseline: 1.1325x; 1.1325x over previous
//
#include <hip/hip_runtime.h>
#include <hip/hip_bf16.h>

// B=16, S=2048, D=512 attention with sum-pool over queries.
// out[b] = ((sum_q softmax(X M X^T * scale)[q,:]) @ X_b) @ Wv,  M = Wq Wk^T.
// log2(e)/sqrt(D) folded into M so exponentials are native exp2.
// GEMM core uses K-chunk XOR swizzle so ds_read_b128 fragment reads are 2-way
// (free) instead of 8-way bank-conflicted, while keeping global_load_lds's
// wave-uniform LDS destination pattern intact.

#define S_LEN 2048
#define D_DIM 512
#define BATCH 16

typedef short bf16x8 __attribute__((ext_vector_type(8)));
typedef float f32x4 __attribute__((ext_vector_type(4)));

typedef __attribute__((address_space(3))) void lds_void_t;
typedef const __attribute__((address_space(1))) void gbl_void_t;

__device__ __forceinline__ void async_copy16(const void* g, void* l) {
  __builtin_amdgcn_global_load_lds((gbl_void_t*)g, (lds_void_t*)l, 16, 0, 0);
}

__device__ __forceinline__ unsigned short f2bf(float f) {
  unsigned u = __float_as_uint(f);
  u += 0x7fff + ((u >> 16) & 1);   // round-to-nearest-even
  return (unsigned short)(u >> 16);
}
__device__ __forceinline__ float bf2f(unsigned short h) {
  return __uint_as_float((unsigned)h << 16);
}

// ---------------- NT GEMM core: C(128x128) = A[M,K] * B[N,K]^T, bf16 in, fp32 acc.
// 256 threads = 4 waves (2x2 of 64x64). K multiple of 32.
__device__ __forceinline__ void gemm_core_nt(
    const unsigned short* __restrict__ A, long lda,
    const unsigned short* __restrict__ B, long ldb,
    int K, unsigned short* As, unsigned short* Bs, f32x4 acc[4][4])
{
  const int tid  = threadIdx.x;
  const int lane = tid & 63;
  const int w    = tid >> 6;
  const int wm   = w >> 1, wn = w & 1;
  const int r16  = lane & 15;
  const int kq   = lane >> 4;

  // staging: 16B chunk j -> LDS slot j*16B; slot (row=j>>2, c=j&3) receives
  // global k-chunk (c - (row>>1)) & 3  [swizzle]
  const int j0 = w * 64 + lane;         // slots 0..255   -> rows 0..63
  const int j1 = (w + 4) * 64 + lane;   // slots 256..511 -> rows 64..127
  const int r0 = j0 >> 2, cc0 = (((j0 & 3) - (r0 >> 1)) & 3);
  const int r1 = j1 >> 2, cc1 = (((j1 & 3) - (r1 >> 1)) & 3);

  const long a0 = (long)r0 * lda + cc0 * 8;
  const long a1 = (long)r1 * lda + cc1 * 8;
  const long b0 = (long)r0 * ldb + cc0 * 8;
  const long b1 = (long)r1 * ldb + cc1 * 8;

  // fragment read offsets (elements), swizzled to match
  int aoff[4], boff[4];
#pragma unroll
  for (int mt = 0; mt < 4; ++mt) {
    const int row = wm * 64 + mt * 16 + r16;
    aoff[mt] = row * 32 + (((row >> 1) + kq) & 3) * 8;
  }
#pragma unroll
  for (int nt = 0; nt < 4; ++nt) {
    const int row = wn * 64 + nt * 16 + r16;
    boff[nt] = row * 32 + (((row >> 1) + kq) & 3) * 8;
  }

  for (int k0 = 0; k0 < K; k0 += 32) {
    __syncthreads();   // previous iter's ds_reads complete before overwrite
    async_copy16(A + a0 + k0, (char*)As + (w    ) * 1024);
    async_copy16(A + a1 + k0, (char*)As + (w + 4) * 1024);
    async_copy16(B + b0 + k0, (char*)Bs + (w    ) * 1024);
    async_copy16(B + b1 + k0, (char*)Bs + (w + 4) * 1024);
    __syncthreads();   // drains vmcnt before barrier -> staging visible

    bf16x8 af[4], bg[4];
#pragma unroll
    for (int mt = 0; mt < 4; ++mt) af[mt] = *(const bf16x8*)&As[aoff[mt]];
#pragma unroll
    for (int nt = 0; nt < 4; ++nt) bg[nt] = *(const bf16x8*)&Bs[boff[nt]];
#pragma unroll
    for (int mt = 0; mt < 4; ++mt)
#pragma unroll
      for (int nt = 0; nt < 4; ++nt)
        acc[mt][nt] = __builtin_amdgcn_mfma_f32_16x16x32_bf16(af[mt], bg[nt], acc[mt][nt], 0, 0, 0);
  }
}

// ---------------- small utility kernels
__global__ __launch_bounds__(256) void k_zero(float* __restrict__ p, int n) {
  int i = blockIdx.x * 256 + threadIdx.x;
  if (i < n) p[i] = 0.0f;
}

__global__ __launch_bounds__(256) void k_cast(const float* __restrict__ s, unsigned short* __restrict__ d) {
  int i = (blockIdx.x * 256 + threadIdx.x) * 4;  // grids sized exactly
  float4 v = *(const float4*)(s + i);
  ushort4 o;
  o.x = f2bf(v.x); o.y = f2bf(v.y); o.z = f2bf(v.z); o.w = f2bf(v.w);
  *(ushort4*)(d + i) = o;
}

// ---------------- generic NT GEMM with bf16 output (used for Mt and Y)
__global__ __launch_bounds__(256) void k_gemm_bf16out(
    const unsigned short* __restrict__ A, long lda,
    const unsigned short* __restrict__ B, long ldb, int K,
    unsigned short* __restrict__ C, long ldc, float scale)
{
  __shared__ alignas(16) unsigned short As[128 * 32];
  __shared__ alignas(16) unsigned short Bs[128 * 32];
  f32x4 acc[4][4] = {};
  const long am0 = (long)blockIdx.y * 128;
  const long bn0 = (long)blockIdx.x * 128;
  gemm_core_nt(A + am0 * lda, lda, B + bn0 * ldb, ldb, K, As, Bs, acc);

  const int lane = threadIdx.x & 63;
  const int w = threadIdx.x >> 6, wm = w >> 1, wn = w & 1;
  const long row0 = am0 + wm * 64 + (lane >> 4) * 4;
  const long col0 = bn0 + wn * 64 + (lane & 15);
#pragma unroll
  for (int mt = 0; mt < 4; ++mt)
#pragma unroll
    for (int nt = 0; nt < 4; ++nt)
#pragma unroll
      for (int r = 0; r < 4; ++r)
        C[(row0 + mt * 16 + r) * ldc + col0 + nt * 16] = f2bf(acc[mt][nt][r] * scale);
}

// ---------------- pass A with E store: scores -> exp2 -> row sums + E[b,q,k] (bf16)
__global__ __launch_bounds__(256) void k_passAE(
    const unsigned short* __restrict__ Ybf, const unsigned short* __restrict__ Xbf,
    float* __restrict__ lrow, unsigned short* __restrict__ E)
{
  __shared__ alignas(16) unsigned short As[128 * 32];
  __shared__ alignas(16) unsigned short Bs[128 * 32];
  f32x4 acc[4][4] = {};
  const int b = blockIdx.z;
  const long q0 = (long)blockIdx.y * 128;
  const long n0 = (long)blockIdx.x * 128;
  gemm_core_nt(Ybf + ((long)b * S_LEN + q0) * D_DIM, D_DIM,
               Xbf + ((long)b * S_LEN + n0) * D_DIM, D_DIM, D_DIM, As, Bs, acc);

  const int lane = threadIdx.x & 63;
  const int w = threadIdx.x >> 6, wm = w >> 1, wn = w & 1;
  const long col0 = n0 + wn * 64 + (lane & 15);
  unsigned short* Eb = E + (long)b * S_LEN * S_LEN;
#pragma unroll
  for (int mt = 0; mt < 4; ++mt) {
#pragma unroll
    for (int r = 0; r < 4; ++r) {
      const long qq = q0 + wm * 64 + mt * 16 + (lane >> 4) * 4 + r;
      float ev[4];
      float s = 0.0f;
#pragma unroll
      for (int nt = 0; nt < 4; ++nt) { ev[nt] = __builtin_amdgcn_exp2f(acc[mt][nt][r]); s += ev[nt]; }
#pragma unroll
      for (int nt = 0; nt < 4; ++nt) Eb[qq * S_LEN + col0 + nt * 16] = f2bf(ev[nt]);
      s += __shfl_xor(s, 1, 64);
      s += __shfl_xor(s, 2, 64);
      s += __shfl_xor(s, 4, 64);
      s += __shfl_xor(s, 8, 64);
      if ((lane & 15) == 0) atomicAdd(&lrow[(long)b * S_LEN + qq], s);
    }
  }
}

// ---------------- w[b,k] = sum_q E[b,q,k] / l[b,q]   (memory-bound column reduce)
__global__ __launch_bounds__(256) void k_wsum(
    const unsigned short* __restrict__ E, const float* __restrict__ lrow,
    float* __restrict__ wcol)
{
  __shared__ float rl[128];
  const int b = blockIdx.z;
  const int q0 = blockIdx.y * 128;
  const int k = blockIdx.x * 1024 + threadIdx.x * 4;
  const float* lp = lrow + (long)b * S_LEN + q0;
  if (threadIdx.x < 128) rl[threadIdx.x] = 1.0f / lp[threadIdx.x];
  __syncthreads();

  const unsigned short* Ep = E + ((long)b * S_LEN + q0) * S_LEN + k;
  float a0 = 0, a1 = 0, a2 = 0, a3 = 0;
#pragma unroll 4
  for (int q = 0; q < 128; ++q) {
    ushort4 e = *(const ushort4*)(Ep + (long)q * S_LEN);
    const float r = rl[q];
    a0 += bf2f(e.x) * r; a1 += bf2f(e.y) * r;
    a2 += bf2f(e.z) * r; a3 += bf2f(e.w) * r;
  }
  float* wp = wcol + (long)b * S_LEN + k;
  atomicAdd(wp + 0, a0); atomicAdd(wp + 1, a1);
  atomicAdd(wp + 2, a2); atomicAdd(wp + 3, a3);
}

// ---------------- fallback pass A (no E store)
__global__ __launch_bounds__(256) void k_passA(
    const unsigned short* __restrict__ Ybf, const unsigned short* __restrict__ Xbf,
    float* __restrict__ lrow)
{
  __shared__ alignas(16) unsigned short As[128 * 32];
  __shared__ alignas(16) unsigned short Bs[128 * 32];
  f32x4 acc[4][4] = {};
  const int b = blockIdx.z;
  const long q0 = (long)blockIdx.y * 128;
  const long n0 = (long)blockIdx.x * 128;
  gemm_core_nt(Ybf + ((long)b * S_LEN + q0) * D_DIM, D_DIM,
               Xbf + ((long)b * S_LEN + n0) * D_DIM, D_DIM, D_DIM, As, Bs, acc);

  const int lane = threadIdx.x & 63;
  const int w = threadIdx.x >> 6, wm = w >> 1;
#pragma unroll
  for (int mt = 0; mt < 4; ++mt) {
#pragma unroll
    for (int r = 0; r < 4; ++r) {
      float s = 0.0f;
#pragma unroll
      for (int nt = 0; nt < 4; ++nt) s += __builtin_amdgcn_exp2f(acc[mt][nt][r]);
      s += __shfl_xor(s, 1, 64);
      s += __shfl_xor(s, 2, 64);
      s += __shfl_xor(s, 4, 64);
      s += __shfl_xor(s, 8, 64);
      if ((lane & 15) == 0)
        atomicAdd(&lrow[(long)b * S_LEN + q0 + wm * 64 + mt * 16 + (lane >> 4) * 4 + r], s);
    }
  }
}

// ---------------- fallback pass B: recompute scores, column sums into w[b,k]
__global__ __launch_bounds__(256) void k_passB(
    const unsigned short* __restrict__ Ybf, const unsigned short* __restrict__ Xbf,
    const float* __restrict__ lrow, float* __restrict__ wcol)
{
  __shared__ alignas(16) unsigned short As[128 * 32];
  __shared__ alignas(16) unsigned short Bs[128 * 32];
  f32x4 acc[4][4] = {};
  const int b = blockIdx.z;
  const long q0 = (long)blockIdx.y * 128;
  const long n0 = (long)blockIdx.x * 128;
  gemm_core_nt(Ybf + ((long)b * S_LEN + q0) * D_DIM, D_DIM,
               Xbf + ((long)b * S_LEN + n0) * D_DIM, D_DIM, D_DIM, As, Bs, acc);

  const int lane = threadIdx.x & 63;
  const int w = threadIdx.x >> 6, wm = w >> 1, wn = w & 1;
  float csv[4] = {0.0f, 0.0f, 0.0f, 0.0f};
#pragma unroll
  for (int mt = 0; mt < 4; ++mt) {
    const float4 lv = *(const float4*)&lrow[(long)b * S_LEN + q0 + wm * 64 + mt * 16 + (lane >> 4) * 4];
    const float rv[4] = {1.0f / lv.x, 1.0f / lv.y, 1.0f / lv.z, 1.0f / lv.w};
#pragma unroll
    for (int nt = 0; nt < 4; ++nt)
#pragma unroll
      for (int r = 0; r < 4; ++r)
        csv[nt] += __builtin_amdgcn_exp2f(acc[mt][nt][r]) * rv[r];
  }
#pragma unroll
  for (int nt = 0; nt < 4; ++nt) {
    csv[nt] += __shfl_xor(csv[nt], 16, 64);
    csv[nt] += __shfl_xor(csv[nt], 32, 64);
  }
  if (lane < 16) {
#pragma unroll
    for (int nt = 0; nt < 4; ++nt)
      atomicAdd(&wcol[(long)b * S_LEN + n0 + wn * 64 + nt * 16 + lane], csv[nt]);
  }
}

// ---------------- t[b,d] = sum_k w[b,k] * X[b,k,d]  (fp32 X for accuracy)
__global__ __launch_bounds__(256) void k_t(
    const float* __restrict__ X, const float* __restrict__ wcol, float* __restrict__ tvec)
{
  const int b = blockIdx.z;
  const int d = blockIdx.x * 256 + threadIdx.x;
  const int k0 = blockIdx.y * 256;
  const float* Xp = X + ((long)b * S_LEN + k0) * D_DIM + d;
  const float* wp = wcol + (long)b * S_LEN + k0;
  float acc = 0.0f;
#pragma unroll 4
  for (int k = 0; k < 256; ++k) acc += wp[k] * Xp[(long)k * D_DIM];
  atomicAdd(&tvec[b * D_DIM + d], acc);
}

// ---------------- out[b,e] = sum_d t[b,d] * Wv[d,e]  (fp32)
__global__ __launch_bounds__(512) void k_out(
    const float* __restrict__ tvec, const float* __restrict__ Wv, float* __restrict__ out)
{
  __shared__ float tl[128];
  const int b = blockIdx.y;
  const int d0 = blockIdx.x * 128;
  const int e = threadIdx.x;
  if (e < 128) tl[e] = tvec[b * D_DIM + d0 + e];
  __syncthreads();
  float acc = 0.0f;
#pragma unroll 4
  for (int d = 0; d < 128; ++d) acc += tl[d] * Wv[(long)(d0 + d) * D_DIM + e];
  atomicAdd(&out[b * D_DIM + e], acc);
}

extern "C" void kernel_launch(void* const* d_in, const int* in_sizes, int n_in,
                              void* d_out, int out_size, void* d_ws, size_t ws_size,
                              hipStream_t stream) {
  const float* X  = (const float*)d_in[0];  // [16,2048,512]
  const float* Wq = (const float*)d_in[1];  // [512,512]
  const float* Wk = (const float*)d_in[2];
  const float* Wv = (const float*)d_in[3];
  float* out = (float*)d_out;               // [16,512]

  char* ws = (char*)d_ws;
  unsigned short* Xbf = (unsigned short*)(ws);              // 32 MB
  unsigned short* Ybf = (unsigned short*)(ws + 33554432);   // 32 MB
  unsigned short* Mt  = (unsigned short*)(ws + 67108864);   // 512 KB (Mt[e,d] = M[d,e]*scale)
  unsigned short* Wqb = (unsigned short*)(ws + 67633152);   // 512 KB
  unsigned short* Wkb = (unsigned short*)(ws + 68157440);   // 512 KB
  float* lrow = (float*)(ws + 68681728);                    // 128 KB  l[b,q]
  float* wcol = (float*)(ws + 68812800);                    // 128 KB  w[b,k]
  float* tvec = (float*)(ws + 68943872);                    // 32 KB   t[b,d]
  unsigned short* E = (unsigned short*)(ws + 69206016);     // 134.2 MB E[b,q,k] (optional)
  const bool bigws = ws_size >= (size_t)69206016 + (size_t)134217728;

  // zero accumulators (ws/out are poisoned 0xAA before every call)
  k_zero<<<288, 256, 0, stream>>>(lrow, 73728);     // lrow+wcol+tvec contiguous
  k_zero<<<32, 256, 0, stream>>>(out, BATCH * D_DIM);

  // bf16 casts
  k_cast<<<16384, 256, 0, stream>>>(X,  Xbf);   // 16,777,216 elems
  k_cast<<<256,   256, 0, stream>>>(Wq, Wqb);   // 262,144
  k_cast<<<256,   256, 0, stream>>>(Wk, Wkb);

  // Mt[e,d] = (log2(e)/sqrt(512)) * sum_c Wk[e,c] Wq[d,c]
  const float scale = 1.4426950408889634f / 22.627416997969522f;
  k_gemm_bf16out<<<dim3(4, 4), 256, 0, stream>>>(Wkb, 512, Wqb, 512, 512, Mt, 512, scale);

  // Y[i,e] = sum_d Xbf[i,d] * Mt[e,d]   (M = B*S = 32768 rows)
  k_gemm_bf16out<<<dim3(4, 256), 256, 0, stream>>>(Xbf, 512, Mt, 512, 512, Ybf, 512, 1.0f);

  if (bigws) {
    // single GEMM pass storing E, then memory-bound column reduce
    k_passAE<<<dim3(16, 16, 16), 256, 0, stream>>>(Ybf, Xbf, lrow, E);
    k_wsum<<<dim3(2, 16, 16), 256, 0, stream>>>(E, lrow, wcol);
  } else {
    k_passA<<<dim3(16, 16, 16), 256, 0, stream>>>(Ybf, Xbf, lrow);
    k_passB<<<dim3(16, 16, 16), 256, 0, stream>>>(Ybf, Xbf, lrow, wcol);
  }

  // t = w @ X (fp32), out = t @ Wv (fp32)
  k_t<<<dim3(2, 8, 16), 256, 0, stream>>>(X, wcol, tvec);
  k_out<<<dim3(4, 16), 512, 0, stream>>>(tvec, Wv, out);
}

// Round 3
// 324.141 us; speedup vs baseline: 1.1751x; 1.0377x over previous
//
#include <hip/hip_runtime.h>
#include <hip/hip_bf16.h>

// B=16, S=2048, D=512 attention with sum-pool over queries.
// out[b] = ((sum_q softmax(X M X^T * scale)[q,:]) @ X_b) @ Wv,  M = Wq Wk^T.
// log2(e)/sqrt(D) folded into M so exponentials are native exp2.
// E = exp2(scores) stored as custom 1-byte fp8 (top-12-bits-of-f32 minus 0x3C0:
// 4 exp-ish bits beyond e4m3 range, 3 mantissa bits, decode = (b+0x3C0)<<20).
// E layout is tiled [b][qt][kt][col(128)][row4(32)] dwords (4 rows packed/dword)
// so both the passAE store (via LDS repack) and the wsum read are coalesced.

#define S_LEN 2048
#define D_DIM 512
#define BATCH 16

typedef short bf16x8 __attribute__((ext_vector_type(8)));
typedef float f32x4 __attribute__((ext_vector_type(4)));

typedef __attribute__((address_space(3))) void lds_void_t;
typedef const __attribute__((address_space(1))) void gbl_void_t;

__device__ __forceinline__ void async_copy16(const void* g, void* l) {
  __builtin_amdgcn_global_load_lds((gbl_void_t*)g, (lds_void_t*)l, 16, 0, 0);
}

__device__ __forceinline__ unsigned short f2bf(float f) {
  unsigned u = __float_as_uint(f);
  u += 0x7fff + ((u >> 16) & 1);   // round-to-nearest-even
  return (unsigned short)(u >> 16);
}
__device__ __forceinline__ float bf2f(unsigned short h) {
  return __uint_as_float((unsigned)h << 16);
}

// custom fp8 for E (E > 0 always): keep exp8+mant3 (top 12 bits), bias-shift.
__device__ __forceinline__ unsigned enc8(float x) {
  unsigned u = __float_as_uint(x);
  unsigned t = (u + 0x7FFFFu + ((u >> 20) & 1u)) >> 20;  // RNE to 3 mantissa bits
  int b = (int)t - 0x3C0;
  b = b < 0 ? 0 : (b > 127 ? 127 : b);
  return (unsigned)b;
}
__device__ __forceinline__ float dec8(unsigned b) {
  return b ? __uint_as_float((b + 0x3C0u) << 20) : 0.0f;
}

// ---------------- NT GEMM core: C(128x128) = A[M,K] * B[N,K]^T, bf16 in, fp32 acc.
// 256 threads = 4 waves (2x2 of 64x64). K multiple of 32. K-chunk swizzle keeps
// ds_read_b128 fragment reads at free 2-way bank aliasing (verified: conflicts=0).
__device__ __forceinline__ void gemm_core_nt(
    const unsigned short* __restrict__ A, long lda,
    const unsigned short* __restrict__ B, long ldb,
    int K, unsigned short* As, unsigned short* Bs, f32x4 acc[4][4])
{
  const int tid  = threadIdx.x;
  const int lane = tid & 63;
  const int w    = tid >> 6;
  const int wm   = w >> 1, wn = w & 1;
  const int r16  = lane & 15;
  const int kq   = lane >> 4;

  const int j0 = w * 64 + lane;         // slots 0..255   -> rows 0..63
  const int j1 = (w + 4) * 64 + lane;   // slots 256..511 -> rows 64..127
  const int r0 = j0 >> 2, cc0 = (((j0 & 3) - (r0 >> 1)) & 3);
  const int r1 = j1 >> 2, cc1 = (((j1 & 3) - (r1 >> 1)) & 3);

  const long a0 = (long)r0 * lda + cc0 * 8;
  const long a1 = (long)r1 * lda + cc1 * 8;
  const long b0 = (long)r0 * ldb + cc0 * 8;
  const long b1 = (long)r1 * ldb + cc1 * 8;

  int aoff[4], boff[4];
#pragma unroll
  for (int mt = 0; mt < 4; ++mt) {
    const int row = wm * 64 + mt * 16 + r16;
    aoff[mt] = row * 32 + (((row >> 1) + kq) & 3) * 8;
  }
#pragma unroll
  for (int nt = 0; nt < 4; ++nt) {
    const int row = wn * 64 + nt * 16 + r16;
    boff[nt] = row * 32 + (((row >> 1) + kq) & 3) * 8;
  }

  for (int k0 = 0; k0 < K; k0 += 32) {
    __syncthreads();
    async_copy16(A + a0 + k0, (char*)As + (w    ) * 1024);
    async_copy16(A + a1 + k0, (char*)As + (w + 4) * 1024);
    async_copy16(B + b0 + k0, (char*)Bs + (w    ) * 1024);
    async_copy16(B + b1 + k0, (char*)Bs + (w + 4) * 1024);
    __syncthreads();

    bf16x8 af[4], bg[4];
#pragma unroll
    for (int mt = 0; mt < 4; ++mt) af[mt] = *(const bf16x8*)&As[aoff[mt]];
#pragma unroll
    for (int nt = 0; nt < 4; ++nt) bg[nt] = *(const bf16x8*)&Bs[boff[nt]];
#pragma unroll
    for (int mt = 0; mt < 4; ++mt)
#pragma unroll
      for (int nt = 0; nt < 4; ++nt)
        acc[mt][nt] = __builtin_amdgcn_mfma_f32_16x16x32_bf16(af[mt], bg[nt], acc[mt][nt], 0, 0, 0);
  }
}

// ---------------- small utility kernels
__global__ __launch_bounds__(256) void k_zero(float* __restrict__ p, int n) {
  int i = blockIdx.x * 256 + threadIdx.x;
  if (i < n) p[i] = 0.0f;
}

__global__ __launch_bounds__(256) void k_cast(const float* __restrict__ s, unsigned short* __restrict__ d) {
  int i = (blockIdx.x * 256 + threadIdx.x) * 4;
  float4 v = *(const float4*)(s + i);
  ushort4 o;
  o.x = f2bf(v.x); o.y = f2bf(v.y); o.z = f2bf(v.z); o.w = f2bf(v.w);
  *(ushort4*)(d + i) = o;
}

// both 512x512 weight casts in one launch (grid 512)
__global__ __launch_bounds__(256) void k_castW(
    const float* __restrict__ a, const float* __restrict__ b,
    unsigned short* __restrict__ da, unsigned short* __restrict__ db)
{
  const int blk = blockIdx.x;
  const float* s = (blk < 256) ? a : b;
  unsigned short* d = (blk < 256) ? da : db;
  int i = ((blk & 255) * 256 + threadIdx.x) * 4;
  float4 v = *(const float4*)(s + i);
  ushort4 o;
  o.x = f2bf(v.x); o.y = f2bf(v.y); o.z = f2bf(v.z); o.w = f2bf(v.w);
  *(ushort4*)(d + i) = o;
}

// ---------------- generic NT GEMM with bf16 output (used for Mt and Y)
__global__ __launch_bounds__(256) void k_gemm_bf16out(
    const unsigned short* __restrict__ A, long lda,
    const unsigned short* __restrict__ B, long ldb, int K,
    unsigned short* __restrict__ C, long ldc, float scale)
{
  __shared__ alignas(16) unsigned short As[128 * 32];
  __shared__ alignas(16) unsigned short Bs[128 * 32];
  f32x4 acc[4][4] = {};
  const long am0 = (long)blockIdx.y * 128;
  const long bn0 = (long)blockIdx.x * 128;
  gemm_core_nt(A + am0 * lda, lda, B + bn0 * ldb, ldb, K, As, Bs, acc);

  const int lane = threadIdx.x & 63;
  const int w = threadIdx.x >> 6, wm = w >> 1, wn = w & 1;
  const long row0 = am0 + wm * 64 + (lane >> 4) * 4;
  const long col0 = bn0 + wn * 64 + (lane & 15);
#pragma unroll
  for (int mt = 0; mt < 4; ++mt)
#pragma unroll
    for (int nt = 0; nt < 4; ++nt)
#pragma unroll
      for (int r = 0; r < 4; ++r)
        C[(row0 + mt * 16 + r) * ldc + col0 + nt * 16] = f2bf(acc[mt][nt][r] * scale);
}

// ---------------- pass A: scores -> exp2 -> row sums (atomic) + fp8 E (tiled, coalesced)
union SMemAE {
  struct { unsigned short As[128 * 32]; unsigned short Bs[128 * 32]; } s;
  unsigned E32[128 * 36];   // [col][r4] with stride-36 pad (banks 2-way = free)
};

__global__ __launch_bounds__(256) void k_passAE(
    const unsigned short* __restrict__ Ybf, const unsigned short* __restrict__ Xbf,
    float* __restrict__ lrow, unsigned* __restrict__ E)
{
  __shared__ SMemAE sm;
  f32x4 acc[4][4] = {};
  const int b = blockIdx.z, qt = blockIdx.y, kt = blockIdx.x;
  const long q0 = (long)qt * 128;
  const long n0 = (long)kt * 128;
  gemm_core_nt(Ybf + ((long)b * S_LEN + q0) * D_DIM, D_DIM,
               Xbf + ((long)b * S_LEN + n0) * D_DIM, D_DIM, D_DIM,
               sm.s.As, sm.s.Bs, acc);

  const int lane = threadIdx.x & 63;
  const int w = threadIdx.x >> 6, wm = w >> 1, wn = w & 1;
  const int r16 = lane & 15, quad = lane >> 4;

  __syncthreads();   // all waves' ds_reads done before As/Bs is reused as E32

#pragma unroll
  for (int mt = 0; mt < 4; ++mt) {
    float rs[4] = {0.f, 0.f, 0.f, 0.f};
#pragma unroll
    for (int nt = 0; nt < 4; ++nt) {
      unsigned dw = 0;
#pragma unroll
      for (int r = 0; r < 4; ++r) {
        float e = __builtin_amdgcn_exp2f(acc[mt][nt][r]);
        rs[r] += e;
        dw |= enc8(e) << (8 * r);
      }
      const int col = wn * 64 + nt * 16 + r16;
      const int r4  = wm * 16 + mt * 4 + quad;
      sm.E32[col * 36 + r4] = dw;
    }
#pragma unroll
    for (int r = 0; r < 4; ++r) {
      float s = rs[r];
      s += __shfl_xor(s, 1, 64);
      s += __shfl_xor(s, 2, 64);
      s += __shfl_xor(s, 4, 64);
      s += __shfl_xor(s, 8, 64);
      if (r16 == 0)
        atomicAdd(&lrow[(long)b * S_LEN + q0 + wm * 64 + mt * 16 + quad * 4 + r], s);
    }
  }
  __syncthreads();

  // cooperative coalesced store: 16 KB tile as 4x (64 lanes x dwordx4 = 1 KB)
  unsigned* Eg = E + (((long)(b * 16 + qt)) * 16 + kt) * 4096;
  const int t = threadIdx.x;
#pragma unroll
  for (int p = 0; p < 4; ++p) {
    const int n = p * 256 + t;            // uint4 index 0..1023
    const int col = n >> 3, hj = n & 7;   // global dwords n*4.. = col*32 + hj*4..
    uint4 v = *(const uint4*)&sm.E32[col * 36 + hj * 4];
    *(uint4*)(Eg + n * 4) = v;
  }
}

// ---------------- w[b,k] += sum_q E[b,q,k]/l[b,q]  (tiled-layout, coalesced reads)
__global__ __launch_bounds__(256) void k_wsum(
    const unsigned* __restrict__ E, const float* __restrict__ lrow,
    float* __restrict__ wcol)
{
  __shared__ float rl[512];
  const int kt = blockIdx.x, qq = blockIdx.y, b = blockIdx.z;
  const int tid = threadIdx.x;
  {
    const float* lp = lrow + (long)b * S_LEN + qq * 512;
    rl[tid]       = 1.0f / lp[tid];
    rl[tid + 256] = 1.0f / lp[tid + 256];
  }
  __syncthreads();
  const int col = tid & 127, qsel = tid >> 7;
  float acc = 0.0f;
#pragma unroll
  for (int qt2 = 0; qt2 < 2; ++qt2) {
    const int qtl = qsel * 2 + qt2;              // local q-tile 0..3
    const int qt = qq * 4 + qtl;
    const unsigned* Ep = E + (((long)(b * 16 + qt)) * 16 + kt) * 4096 + col * 32;
    const float* rlq = rl + qtl * 128;
#pragma unroll
    for (int j = 0; j < 8; ++j) {
      uint4 v = *(const uint4*)(Ep + j * 4);
      const unsigned dws[4] = {v.x, v.y, v.z, v.w};
#pragma unroll
      for (int i = 0; i < 4; ++i) {
        const unsigned dv = dws[i];
        const float* r = rlq + j * 16 + i * 4;
        acc += dec8( dv        & 0xFFu) * r[0];
        acc += dec8((dv >>  8) & 0xFFu) * r[1];
        acc += dec8((dv >> 16) & 0xFFu) * r[2];
        acc += dec8((dv >> 24)        ) * r[3];
      }
    }
  }
  atomicAdd(&wcol[(long)b * S_LEN + kt * 128 + col], acc);
}

// ---------------- fallback pass A (no E store) and pass B (recompute)
__global__ __launch_bounds__(256) void k_passA(
    const unsigned short* __restrict__ Ybf, const unsigned short* __restrict__ Xbf,
    float* __restrict__ lrow)
{
  __shared__ alignas(16) unsigned short As[128 * 32];
  __shared__ alignas(16) unsigned short Bs[128 * 32];
  f32x4 acc[4][4] = {};
  const int b = blockIdx.z;
  const long q0 = (long)blockIdx.y * 128;
  const long n0 = (long)blockIdx.x * 128;
  gemm_core_nt(Ybf + ((long)b * S_LEN + q0) * D_DIM, D_DIM,
               Xbf + ((long)b * S_LEN + n0) * D_DIM, D_DIM, D_DIM, As, Bs, acc);

  const int lane = threadIdx.x & 63;
  const int w = threadIdx.x >> 6, wm = w >> 1;
#pragma unroll
  for (int mt = 0; mt < 4; ++mt) {
#pragma unroll
    for (int r = 0; r < 4; ++r) {
      float s = 0.0f;
#pragma unroll
      for (int nt = 0; nt < 4; ++nt) s += __builtin_amdgcn_exp2f(acc[mt][nt][r]);
      s += __shfl_xor(s, 1, 64);
      s += __shfl_xor(s, 2, 64);
      s += __shfl_xor(s, 4, 64);
      s += __shfl_xor(s, 8, 64);
      if ((lane & 15) == 0)
        atomicAdd(&lrow[(long)b * S_LEN + q0 + wm * 64 + mt * 16 + (lane >> 4) * 4 + r], s);
    }
  }
}

__global__ __launch_bounds__(256) void k_passB(
    const unsigned short* __restrict__ Ybf, const unsigned short* __restrict__ Xbf,
    const float* __restrict__ lrow, float* __restrict__ wcol)
{
  __shared__ alignas(16) unsigned short As[128 * 32];
  __shared__ alignas(16) unsigned short Bs[128 * 32];
  f32x4 acc[4][4] = {};
  const int b = blockIdx.z;
  const long q0 = (long)blockIdx.y * 128;
  const long n0 = (long)blockIdx.x * 128;
  gemm_core_nt(Ybf + ((long)b * S_LEN + q0) * D_DIM, D_DIM,
               Xbf + ((long)b * S_LEN + n0) * D_DIM, D_DIM, D_DIM, As, Bs, acc);

  const int lane = threadIdx.x & 63;
  const int w = threadIdx.x >> 6, wm = w >> 1, wn = w & 1;
  float csv[4] = {0.0f, 0.0f, 0.0f, 0.0f};
#pragma unroll
  for (int mt = 0; mt < 4; ++mt) {
    const float4 lv = *(const float4*)&lrow[(long)b * S_LEN + q0 + wm * 64 + mt * 16 + (lane >> 4) * 4];
    const float rv[4] = {1.0f / lv.x, 1.0f / lv.y, 1.0f / lv.z, 1.0f / lv.w};
#pragma unroll
    for (int nt = 0; nt < 4; ++nt)
#pragma unroll
      for (int r = 0; r < 4; ++r)
        csv[nt] += __builtin_amdgcn_exp2f(acc[mt][nt][r]) * rv[r];
  }
#pragma unroll
  for (int nt = 0; nt < 4; ++nt) {
    csv[nt] += __shfl_xor(csv[nt], 16, 64);
    csv[nt] += __shfl_xor(csv[nt], 32, 64);
  }
  if (lane < 16) {
#pragma unroll
    for (int nt = 0; nt < 4; ++nt)
      atomicAdd(&wcol[(long)b * S_LEN + n0 + wn * 64 + nt * 16 + lane], csv[nt]);
  }
}

// ---------------- t[b,d] = sum_k w[b,k] * X[b,k,d]  (bf16 X)
__global__ __launch_bounds__(256) void k_t(
    const unsigned short* __restrict__ Xbf, const float* __restrict__ wcol,
    float* __restrict__ tvec)
{
  const int b = blockIdx.z;
  const int d = blockIdx.x * 256 + threadIdx.x;
  const int k0 = blockIdx.y * 256;
  const unsigned short* Xp = Xbf + ((long)b * S_LEN + k0) * D_DIM + d;
  const float* wp = wcol + (long)b * S_LEN + k0;
  float acc = 0.0f;
#pragma unroll 4
  for (int k = 0; k < 256; ++k) acc += wp[k] * bf2f(Xp[(long)k * D_DIM]);
  atomicAdd(&tvec[b * D_DIM + d], acc);
}

// ---------------- out[b,e] = sum_d t[b,d] * Wv[d,e]  (fp32, non-atomic)
__global__ __launch_bounds__(128) void k_out(
    const float* __restrict__ tvec, const float* __restrict__ Wv, float* __restrict__ out)
{
  __shared__ float tl[512];
  const int b = blockIdx.y;
  const int e = blockIdx.x * 128 + threadIdx.x;
#pragma unroll
  for (int j = 0; j < 4; ++j) tl[threadIdx.x + j * 128] = tvec[b * D_DIM + threadIdx.x + j * 128];
  __syncthreads();
  float acc = 0.0f;
#pragma unroll 4
  for (int d = 0; d < 512; ++d) acc += tl[d] * Wv[(long)d * D_DIM + e];
  out[b * D_DIM + e] = acc;
}

extern "C" void kernel_launch(void* const* d_in, const int* in_sizes, int n_in,
                              void* d_out, int out_size, void* d_ws, size_t ws_size,
                              hipStream_t stream) {
  const float* X  = (const float*)d_in[0];  // [16,2048,512]
  const float* Wq = (const float*)d_in[1];  // [512,512]
  const float* Wk = (const float*)d_in[2];
  const float* Wv = (const float*)d_in[3];
  float* out = (float*)d_out;               // [16,512]

  char* ws = (char*)d_ws;
  unsigned short* Xbf = (unsigned short*)(ws);              // 32 MB
  unsigned short* Ybf = (unsigned short*)(ws + 33554432);   // 32 MB
  unsigned short* Mt  = (unsigned short*)(ws + 67108864);   // 512 KB (Mt[e,d] = M[d,e]*scale)
  unsigned short* Wqb = (unsigned short*)(ws + 67633152);   // 512 KB
  unsigned short* Wkb = (unsigned short*)(ws + 68157440);   // 512 KB
  float* lrow = (float*)(ws + 68681728);                    // 128 KB  l[b,q]
  float* wcol = (float*)(ws + 68812800);                    // 128 KB  w[b,k]
  float* tvec = (float*)(ws + 68943872);                    // 32 KB   t[b,d]
  unsigned* E = (unsigned*)(ws + 69206016);                 // 64 MB   fp8 E, tiled
  const bool bigws = ws_size >= (size_t)69206016 + (size_t)67108864;

  // zero atomic accumulators: lrow+wcol+tvec contiguous (73728 floats)
  k_zero<<<288, 256, 0, stream>>>(lrow, 73728);

  // bf16 casts
  k_cast<<<16384, 256, 0, stream>>>(X, Xbf);                 // 16,777,216 elems
  k_castW<<<512, 256, 0, stream>>>(Wq, Wk, Wqb, Wkb);

  // Mt[e,d] = (log2(e)/sqrt(512)) * sum_c Wk[e,c] Wq[d,c]
  const float scale = 1.4426950408889634f / 22.627416997969522f;
  k_gemm_bf16out<<<dim3(4, 4), 256, 0, stream>>>(Wkb, 512, Wqb, 512, 512, Mt, 512, scale);

  // Y[i,e] = sum_d Xbf[i,d] * Mt[e,d]
  k_gemm_bf16out<<<dim3(4, 256), 256, 0, stream>>>(Xbf, 512, Mt, 512, 512, Ybf, 512, 1.0f);

  if (bigws) {
    k_passAE<<<dim3(16, 16, 16), 256, 0, stream>>>(Ybf, Xbf, lrow, E);
    k_wsum<<<dim3(16, 4, 16), 256, 0, stream>>>(E, lrow, wcol);
  } else {
    k_passA<<<dim3(16, 16, 16), 256, 0, stream>>>(Ybf, Xbf, lrow);
    k_passB<<<dim3(16, 16, 16), 256, 0, stream>>>(Ybf, Xbf, lrow, wcol);
  }

  // t = w @ X (bf16 X), out = t @ Wv (fp32)
  k_t<<<dim3(2, 8, 16), 256, 0, stream>>>(Xbf, wcol, tvec);
  k_out<<<dim3(4, 16), 128, 0, stream>>>(tvec, Wv, out);
}

// Round 4
// 301.199 us; speedup vs baseline: 1.2646x; 1.0762x over previous
//
#include <hip/hip_runtime.h>
#include <hip/hip_bf16.h>

// B=16, S=2048, D=512 attention with sum-pool over queries.
// out[b] = ((sum_q softmax(X M X^T * scale)[q,:]) @ X_b) @ Wv,  M = Wq Wk^T.
// log2(e)/sqrt(D) folded into M so exponentials are native exp2.
// E = exp2(scores) stored as fp8 (HW e4m3 cvt when available; else custom enc8).
// E layout tiled [b][qt][kt][col(128)][row4(32)] dwords; coalesced both sides.
// GEMM core: BK=64 staging (8 barrier-pairs for K=512), rotate-by-row chunk
// swizzle -> ds_read_b128 at free 2-way bank aliasing, global_load_lds dwordx4.

#define S_LEN 2048
#define D_DIM 512
#define BATCH 16

typedef short bf16x8 __attribute__((ext_vector_type(8)));
typedef float f32x4 __attribute__((ext_vector_type(4)));

typedef __attribute__((address_space(3))) void lds_void_t;
typedef const __attribute__((address_space(1))) void gbl_void_t;

__device__ __forceinline__ void async_copy16(const void* g, void* l) {
  __builtin_amdgcn_global_load_lds((gbl_void_t*)g, (lds_void_t*)l, 16, 0, 0);
}

__device__ __forceinline__ unsigned short f2bf(float f) {
  unsigned u = __float_as_uint(f);
  u += 0x7fff + ((u >> 16) & 1);   // RNE
  return (unsigned short)(u >> 16);
}
__device__ __forceinline__ float bf2f(unsigned short h) {
  return __uint_as_float((unsigned)h << 16);
}

#if __has_builtin(__builtin_amdgcn_cvt_pk_fp8_f32) && __has_builtin(__builtin_amdgcn_cvt_f32_fp8)
#define HAVE_FP8CVT 1
#else
#define HAVE_FP8CVT 0
#endif

// fallback custom fp8 (bias-shifted top-12-bits); only used if no HW cvt
__device__ __forceinline__ unsigned enc8(float x) {
  unsigned u = __float_as_uint(x);
  unsigned t = (u + 0x7FFFFu + ((u >> 20) & 1u)) >> 20;
  int b = (int)t - 0x3C0;
  b = b < 0 ? 0 : (b > 127 ? 127 : b);
  return (unsigned)b;
}
__device__ __forceinline__ float dec8(unsigned b) {
  return b ? __uint_as_float((b + 0x3C0u) << 20) : 0.0f;
}

__device__ __forceinline__ unsigned pack4_fp8(float e0, float e1, float e2, float e3) {
#if HAVE_FP8CVT
  unsigned dw = (unsigned)__builtin_amdgcn_cvt_pk_fp8_f32(e0, e1, 0, false);
  dw = (unsigned)__builtin_amdgcn_cvt_pk_fp8_f32(e2, e3, (int)dw, true);
  return dw;
#else
  return enc8(e0) | (enc8(e1) << 8) | (enc8(e2) << 16) | (enc8(e3) << 24);
#endif
}

// ---------------- NT GEMM core: C(128x128) = A[M,K] * B[N,K]^T, bf16 in, fp32 acc.
// 256 threads = 4 waves (2x2 of 64x64). K multiple of 64. BK=64.
// LDS layout: row(128) x slot(8) x 16B; slot s of row r holds k-chunk (s-r)&7.
__device__ __forceinline__ void gemm_core_nt(
    const unsigned short* __restrict__ A, long lda,
    const unsigned short* __restrict__ B, long ldb,
    int K, unsigned short* As, unsigned short* Bs, f32x4 acc[4][4])
{
  const int tid  = threadIdx.x;
  const int lane = tid & 63;
  const int w    = tid >> 6;
  const int wm   = w >> 1, wn = w & 1;
  const int r16  = lane & 15;
  const int kq   = lane >> 4;

  // producer: slot-linear id j -> row r = j>>3, slot s = j&7, chunk c = (s-r)&7
  long asrc[4], bsrc[4];
#pragma unroll
  for (int p = 0; p < 4; ++p) {
    const int j = p * 256 + w * 64 + lane;
    const int r = j >> 3, s = j & 7, c = (s - r) & 7;
    asrc[p] = (long)r * lda + c * 8;
    bsrc[p] = (long)r * ldb + c * 8;
  }

  // consumer: k-step ks (32 wide), chunk c = ks*4+kq, slot (c+row)&7
  int aoff[2][4], boff[2][4];
#pragma unroll
  for (int ks = 0; ks < 2; ++ks) {
#pragma unroll
    for (int t = 0; t < 4; ++t) {
      const int m = wm * 64 + t * 16 + r16;
      aoff[ks][t] = m * 64 + ((ks * 4 + kq + m) & 7) * 8;
      const int n = wn * 64 + t * 16 + r16;
      boff[ks][t] = n * 64 + ((ks * 4 + kq + n) & 7) * 8;
    }
  }

  for (int k0 = 0; k0 < K; k0 += 64) {
    __syncthreads();   // previous iter's ds_reads complete before overwrite
#pragma unroll
    for (int p = 0; p < 4; ++p) {
      async_copy16(A + asrc[p] + k0, (char*)As + (p * 256 + w * 64) * 16);
      async_copy16(B + bsrc[p] + k0, (char*)Bs + (p * 256 + w * 64) * 16);
    }
    __syncthreads();   // vmcnt drained at barrier -> staging visible

#pragma unroll
    for (int ks = 0; ks < 2; ++ks) {
      bf16x8 af[4], bg[4];
#pragma unroll
      for (int mt = 0; mt < 4; ++mt) af[mt] = *(const bf16x8*)&As[aoff[ks][mt]];
#pragma unroll
      for (int nt = 0; nt < 4; ++nt) bg[nt] = *(const bf16x8*)&Bs[boff[ks][nt]];
#pragma unroll
      for (int mt = 0; mt < 4; ++mt)
#pragma unroll
        for (int nt = 0; nt < 4; ++nt)
          acc[mt][nt] = __builtin_amdgcn_mfma_f32_16x16x32_bf16(af[mt], bg[nt], acc[mt][nt], 0, 0, 0);
    }
  }
}

// ---------------- small utility kernels
__global__ __launch_bounds__(256) void k_zero2(float* __restrict__ p1, int n1,
                                               float* __restrict__ p2, int n2) {
  int i = blockIdx.x * 256 + threadIdx.x;
  if (i < n1) p1[i] = 0.0f;
  i -= n1;
  if (i >= 0 && i < n2) p2[i] = 0.0f;
}

__global__ __launch_bounds__(256) void k_cast(const float* __restrict__ s, unsigned short* __restrict__ d) {
  int i = (blockIdx.x * 256 + threadIdx.x) * 4;
  float4 v = *(const float4*)(s + i);
  ushort4 o;
  o.x = f2bf(v.x); o.y = f2bf(v.y); o.z = f2bf(v.z); o.w = f2bf(v.w);
  *(ushort4*)(d + i) = o;
}

__global__ __launch_bounds__(256) void k_castW(
    const float* __restrict__ a, const float* __restrict__ b,
    unsigned short* __restrict__ da, unsigned short* __restrict__ db)
{
  const int blk = blockIdx.x;
  const float* s = (blk < 256) ? a : b;
  unsigned short* d = (blk < 256) ? da : db;
  int i = ((blk & 255) * 256 + threadIdx.x) * 4;
  float4 v = *(const float4*)(s + i);
  ushort4 o;
  o.x = f2bf(v.x); o.y = f2bf(v.y); o.z = f2bf(v.z); o.w = f2bf(v.w);
  *(ushort4*)(d + i) = o;
}

// ---------------- generic NT GEMM with bf16 output (used for Mt and Y)
__global__ __launch_bounds__(256) void k_gemm_bf16out(
    const unsigned short* __restrict__ A, long lda,
    const unsigned short* __restrict__ B, long ldb, int K,
    unsigned short* __restrict__ C, long ldc, float scale)
{
  __shared__ alignas(16) unsigned short As[128 * 64];
  __shared__ alignas(16) unsigned short Bs[128 * 64];
  f32x4 acc[4][4] = {};
  const long am0 = (long)blockIdx.y * 128;
  const long bn0 = (long)blockIdx.x * 128;
  gemm_core_nt(A + am0 * lda, lda, B + bn0 * ldb, ldb, K, As, Bs, acc);

  const int lane = threadIdx.x & 63;
  const int w = threadIdx.x >> 6, wm = w >> 1, wn = w & 1;
  const long row0 = am0 + wm * 64 + (lane >> 4) * 4;
  const long col0 = bn0 + wn * 64 + (lane & 15);
#pragma unroll
  for (int mt = 0; mt < 4; ++mt)
#pragma unroll
    for (int nt = 0; nt < 4; ++nt)
#pragma unroll
      for (int r = 0; r < 4; ++r)
        C[(row0 + mt * 16 + r) * ldc + col0 + nt * 16] = f2bf(acc[mt][nt][r] * scale);
}

// ---------------- pass A: scores -> exp2 -> row sums (atomic) + fp8 E (tiled)
union alignas(16) SMemAE {
  struct { unsigned short As[128 * 64]; unsigned short Bs[128 * 64]; } s;
  unsigned E32[128 * 36];   // [col][r4], stride-36 pad
};

__global__ __launch_bounds__(256) void k_passAE(
    const unsigned short* __restrict__ Ybf, const unsigned short* __restrict__ Xbf,
    float* __restrict__ lrow, unsigned* __restrict__ E)
{
  __shared__ SMemAE sm;
  f32x4 acc[4][4] = {};
  const int b = blockIdx.z, qt = blockIdx.y, kt = blockIdx.x;
  const long q0 = (long)qt * 128;
  const long n0 = (long)kt * 128;
  gemm_core_nt(Ybf + ((long)b * S_LEN + q0) * D_DIM, D_DIM,
               Xbf + ((long)b * S_LEN + n0) * D_DIM, D_DIM, D_DIM,
               sm.s.As, sm.s.Bs, acc);

  const int lane = threadIdx.x & 63;
  const int w = threadIdx.x >> 6, wm = w >> 1, wn = w & 1;
  const int r16 = lane & 15, quad = lane >> 4;

  __syncthreads();   // all waves' ds_reads done before As/Bs reused as E32

#pragma unroll
  for (int mt = 0; mt < 4; ++mt) {
    float rs[4] = {0.f, 0.f, 0.f, 0.f};
#pragma unroll
    for (int nt = 0; nt < 4; ++nt) {
      float ev[4];
#pragma unroll
      for (int r = 0; r < 4; ++r) {
        ev[r] = __builtin_amdgcn_exp2f(acc[mt][nt][r]);
        rs[r] += ev[r];
      }
      const int col = wn * 64 + nt * 16 + r16;
      const int r4  = wm * 16 + mt * 4 + quad;
      sm.E32[col * 36 + r4] = pack4_fp8(ev[0], ev[1], ev[2], ev[3]);
    }
#pragma unroll
    for (int r = 0; r < 4; ++r) {
      float s = rs[r];
      s += __shfl_xor(s, 1, 64);
      s += __shfl_xor(s, 2, 64);
      s += __shfl_xor(s, 4, 64);
      s += __shfl_xor(s, 8, 64);
      if (r16 == 0)
        atomicAdd(&lrow[(long)b * S_LEN + q0 + wm * 64 + mt * 16 + quad * 4 + r], s);
    }
  }
  __syncthreads();

  // cooperative coalesced store: 16 KB tile as 4x (256 lanes x dwordx4)
  unsigned* Eg = E + (((long)(b * 16 + qt)) * 16 + kt) * 4096;
  const int t = threadIdx.x;
#pragma unroll
  for (int p = 0; p < 4; ++p) {
    const int n = p * 256 + t;            // uint4 index 0..1023
    const int col = n >> 3, hj = n & 7;
    uint4 v = *(const uint4*)&sm.E32[col * 36 + hj * 4];
    *(uint4*)(Eg + n * 4) = v;
  }
}

// ---------------- w[b,k] += sum_q E[b,q,k]/l[b,q]  (tiled-layout, coalesced)
__global__ __launch_bounds__(256) void k_wsum(
    const unsigned* __restrict__ E, const float* __restrict__ lrow,
    float* __restrict__ wcol)
{
  __shared__ float rl[512];
  const int kt = blockIdx.x, qq = blockIdx.y, b = blockIdx.z;
  const int tid = threadIdx.x;
  {
    const float* lp = lrow + (long)b * S_LEN + qq * 512;
    rl[tid]       = 1.0f / lp[tid];
    rl[tid + 256] = 1.0f / lp[tid + 256];
  }
  __syncthreads();
  const int col = tid & 127, qsel = tid >> 7;
  float acc = 0.0f;
#pragma unroll
  for (int qt2 = 0; qt2 < 2; ++qt2) {
    const int qtl = qsel * 2 + qt2;              // local q-tile 0..3
    const int qt = qq * 4 + qtl;
    const unsigned* Ep = E + (((long)(b * 16 + qt)) * 16 + kt) * 4096 + col * 32;
    const float* rlq = rl + qtl * 128;
#pragma unroll
    for (int j = 0; j < 8; ++j) {
      uint4 v = *(const uint4*)(Ep + j * 4);
      const unsigned dws[4] = {v.x, v.y, v.z, v.w};
#pragma unroll
      for (int i = 0; i < 4; ++i) {
        const unsigned dv = dws[i];
        const float* r = rlq + j * 16 + i * 4;
#if HAVE_FP8CVT
        acc += __builtin_amdgcn_cvt_f32_fp8((int)dv, 0) * r[0];
        acc += __builtin_amdgcn_cvt_f32_fp8((int)dv, 1) * r[1];
        acc += __builtin_amdgcn_cvt_f32_fp8((int)dv, 2) * r[2];
        acc += __builtin_amdgcn_cvt_f32_fp8((int)dv, 3) * r[3];
#else
        acc += dec8( dv        & 0xFFu) * r[0];
        acc += dec8((dv >>  8) & 0xFFu) * r[1];
        acc += dec8((dv >> 16) & 0xFFu) * r[2];
        acc += dec8((dv >> 24)        ) * r[3];
#endif
      }
    }
  }
  atomicAdd(&wcol[(long)b * S_LEN + kt * 128 + col], acc);
}

// ---------------- fallback pass A/B (no E store; recompute) for small ws
__global__ __launch_bounds__(256) void k_passA(
    const unsigned short* __restrict__ Ybf, const unsigned short* __restrict__ Xbf,
    float* __restrict__ lrow)
{
  __shared__ alignas(16) unsigned short As[128 * 64];
  __shared__ alignas(16) unsigned short Bs[128 * 64];
  f32x4 acc[4][4] = {};
  const int b = blockIdx.z;
  const long q0 = (long)blockIdx.y * 128;
  const long n0 = (long)blockIdx.x * 128;
  gemm_core_nt(Ybf + ((long)b * S_LEN + q0) * D_DIM, D_DIM,
               Xbf + ((long)b * S_LEN + n0) * D_DIM, D_DIM, D_DIM, As, Bs, acc);

  const int lane = threadIdx.x & 63;
  const int w = threadIdx.x >> 6, wm = w >> 1;
#pragma unroll
  for (int mt = 0; mt < 4; ++mt) {
#pragma unroll
    for (int r = 0; r < 4; ++r) {
      float s = 0.0f;
#pragma unroll
      for (int nt = 0; nt < 4; ++nt) s += __builtin_amdgcn_exp2f(acc[mt][nt][r]);
      s += __shfl_xor(s, 1, 64);
      s += __shfl_xor(s, 2, 64);
      s += __shfl_xor(s, 4, 64);
      s += __shfl_xor(s, 8, 64);
      if ((lane & 15) == 0)
        atomicAdd(&lrow[(long)b * S_LEN + q0 + wm * 64 + mt * 16 + (lane >> 4) * 4 + r], s);
    }
  }
}

__global__ __launch_bounds__(256) void k_passB(
    const unsigned short* __restrict__ Ybf, const unsigned short* __restrict__ Xbf,
    const float* __restrict__ lrow, float* __restrict__ wcol)
{
  __shared__ alignas(16) unsigned short As[128 * 64];
  __shared__ alignas(16) unsigned short Bs[128 * 64];
  f32x4 acc[4][4] = {};
  const int b = blockIdx.z;
  const long q0 = (long)blockIdx.y * 128;
  const long n0 = (long)blockIdx.x * 128;
  gemm_core_nt(Ybf + ((long)b * S_LEN + q0) * D_DIM, D_DIM,
               Xbf + ((long)b * S_LEN + n0) * D_DIM, D_DIM, D_DIM, As, Bs, acc);

  const int lane = threadIdx.x & 63;
  const int w = threadIdx.x >> 6, wm = w >> 1, wn = w & 1;
  float csv[4] = {0.0f, 0.0f, 0.0f, 0.0f};
#pragma unroll
  for (int mt = 0; mt < 4; ++mt) {
    const float4 lv = *(const float4*)&lrow[(long)b * S_LEN + q0 + wm * 64 + mt * 16 + (lane >> 4) * 4];
    const float rv[4] = {1.0f / lv.x, 1.0f / lv.y, 1.0f / lv.z, 1.0f / lv.w};
#pragma unroll
    for (int nt = 0; nt < 4; ++nt)
#pragma unroll
      for (int r = 0; r < 4; ++r)
        csv[nt] += __builtin_amdgcn_exp2f(acc[mt][nt][r]) * rv[r];
  }
#pragma unroll
  for (int nt = 0; nt < 4; ++nt) {
    csv[nt] += __shfl_xor(csv[nt], 16, 64);
    csv[nt] += __shfl_xor(csv[nt], 32, 64);
  }
  if (lane < 16) {
#pragma unroll
    for (int nt = 0; nt < 4; ++nt)
      atomicAdd(&wcol[(long)b * S_LEN + n0 + wn * 64 + nt * 16 + lane], csv[nt]);
  }
}

// ---------------- t[b,d] = sum_k w[b,k] * X[b,k,d]  (bf16 X, k-split for occupancy)
__global__ __launch_bounds__(256) void k_t(
    const unsigned short* __restrict__ Xbf, const float* __restrict__ wcol,
    float* __restrict__ tvec)
{
  const int b = blockIdx.z;
  const int d = blockIdx.x * 256 + threadIdx.x;
  const int k0 = blockIdx.y * 64;
  const unsigned short* Xp = Xbf + ((long)b * S_LEN + k0) * D_DIM + d;
  const float* wp = wcol + (long)b * S_LEN + k0;
  float acc = 0.0f;
#pragma unroll 8
  for (int k = 0; k < 64; ++k) acc += wp[k] * bf2f(Xp[(long)k * D_DIM]);
  atomicAdd(&tvec[b * D_DIM + d], acc);
}

// ---------------- out[b,e] += sum_{d in chunk} t[b,d] * Wv[d,e]  (fp32, d-split)
__global__ __launch_bounds__(128) void k_out(
    const float* __restrict__ tvec, const float* __restrict__ Wv, float* __restrict__ out)
{
  __shared__ float tl[128];
  const int b = blockIdx.y;
  const int d0 = blockIdx.z * 128;
  const int e = blockIdx.x * 128 + threadIdx.x;
  tl[threadIdx.x] = tvec[b * D_DIM + d0 + threadIdx.x];
  __syncthreads();
  float acc = 0.0f;
#pragma unroll 8
  for (int d = 0; d < 128; ++d) acc += tl[d] * Wv[(long)(d0 + d) * D_DIM + e];
  atomicAdd(&out[b * D_DIM + e], acc);
}

extern "C" void kernel_launch(void* const* d_in, const int* in_sizes, int n_in,
                              void* d_out, int out_size, void* d_ws, size_t ws_size,
                              hipStream_t stream) {
  const float* X  = (const float*)d_in[0];  // [16,2048,512]
  const float* Wq = (const float*)d_in[1];  // [512,512]
  const float* Wk = (const float*)d_in[2];
  const float* Wv = (const float*)d_in[3];
  float* out = (float*)d_out;               // [16,512]

  char* ws = (char*)d_ws;
  unsigned short* Xbf = (unsigned short*)(ws);              // 32 MB
  unsigned short* Ybf = (unsigned short*)(ws + 33554432);   // 32 MB
  unsigned short* Mt  = (unsigned short*)(ws + 67108864);   // 512 KB (Mt[e,d] = M[d,e]*scale)
  unsigned short* Wqb = (unsigned short*)(ws + 67633152);   // 512 KB
  unsigned short* Wkb = (unsigned short*)(ws + 68157440);   // 512 KB
  float* lrow = (float*)(ws + 68681728);                    // 128 KB  l[b,q]
  float* wcol = (float*)(ws + 68812800);                    // 128 KB  w[b,k]
  float* tvec = (float*)(ws + 68943872);                    // 32 KB   t[b,d]
  unsigned* E = (unsigned*)(ws + 69206016);                 // 64 MB   fp8 E, tiled
  const bool bigws = ws_size >= (size_t)69206016 + (size_t)67108864;

  // zero atomic accumulators (lrow+wcol+tvec contiguous: 73728 floats) + out
  k_zero2<<<320, 256, 0, stream>>>(lrow, 73728, out, BATCH * D_DIM);

  // bf16 casts
  k_cast<<<16384, 256, 0, stream>>>(X, Xbf);
  k_castW<<<512, 256, 0, stream>>>(Wq, Wk, Wqb, Wkb);

  // Mt[e,d] = (log2(e)/sqrt(512)) * sum_c Wk[e,c] Wq[d,c]
  const float scale = 1.4426950408889634f / 22.627416997969522f;
  k_gemm_bf16out<<<dim3(4, 4), 256, 0, stream>>>(Wkb, 512, Wqb, 512, 512, Mt, 512, scale);

  // Y[i,e] = sum_d Xbf[i,d] * Mt[e,d]
  k_gemm_bf16out<<<dim3(4, 256), 256, 0, stream>>>(Xbf, 512, Mt, 512, 512, Ybf, 512, 1.0f);

  if (bigws) {
    k_passAE<<<dim3(16, 16, 16), 256, 0, stream>>>(Ybf, Xbf, lrow, E);
    k_wsum<<<dim3(16, 4, 16), 256, 0, stream>>>(E, lrow, wcol);
  } else {
    k_passA<<<dim3(16, 16, 16), 256, 0, stream>>>(Ybf, Xbf, lrow);
    k_passB<<<dim3(16, 16, 16), 256, 0, stream>>>(Ybf, Xbf, lrow, wcol);
  }

  // t = w @ X (bf16 X), out = t @ Wv (fp32)
  k_t<<<dim3(2, 32, 16), 256, 0, stream>>>(Xbf, wcol, tvec);
  k_out<<<dim3(4, 16, 4), 128, 0, stream>>>(tvec, Wv, out);
}

// Round 5
// 272.268 us; speedup vs baseline: 1.3990x; 1.1063x over previous
//
#include <hip/hip_runtime.h>
#include <hip/hip_bf16.h>

// B=16, S=2048, D=512 attention with sum-pool over queries.
// out[b] = ((sum_q softmax(X M X^T * scale)[q,:]) @ X_b) @ Wv,  M = Wq Wk^T.
// log2(e)/sqrt(D) folded into M so exponentials are native exp2.
// E = exp2(scores) stored as fp8 (HW e4m3 cvt), tiled layout, coalesced both sides.
// GEMM core: BK=32 (R3-proven best: VGPR 76, 18KB LDS, occ ~30%; BK=64 regressed
// occupancy 30->21% and net dur). K-chunk swizzle keeps ds_read_b128 conflict-free.

#define S_LEN 2048
#define D_DIM 512
#define BATCH 16

typedef short bf16x8 __attribute__((ext_vector_type(8)));
typedef float f32x4 __attribute__((ext_vector_type(4)));

typedef __attribute__((address_space(3))) void lds_void_t;
typedef const __attribute__((address_space(1))) void gbl_void_t;

__device__ __forceinline__ void async_copy16(const void* g, void* l) {
  __builtin_amdgcn_global_load_lds((gbl_void_t*)g, (lds_void_t*)l, 16, 0, 0);
}

__device__ __forceinline__ unsigned short f2bf(float f) {
  unsigned u = __float_as_uint(f);
  u += 0x7fff + ((u >> 16) & 1);   // RNE
  return (unsigned short)(u >> 16);
}
__device__ __forceinline__ float bf2f(unsigned short h) {
  return __uint_as_float((unsigned)h << 16);
}

#if __has_builtin(__builtin_amdgcn_cvt_pk_fp8_f32) && __has_builtin(__builtin_amdgcn_cvt_f32_fp8)
#define HAVE_FP8CVT 1
#else
#define HAVE_FP8CVT 0
#endif

__device__ __forceinline__ unsigned enc8(float x) {
  unsigned u = __float_as_uint(x);
  unsigned t = (u + 0x7FFFFu + ((u >> 20) & 1u)) >> 20;
  int b = (int)t - 0x3C0;
  b = b < 0 ? 0 : (b > 127 ? 127 : b);
  return (unsigned)b;
}
__device__ __forceinline__ float dec8(unsigned b) {
  return b ? __uint_as_float((b + 0x3C0u) << 20) : 0.0f;
}

__device__ __forceinline__ unsigned pack4_fp8(float e0, float e1, float e2, float e3) {
#if HAVE_FP8CVT
  unsigned dw = (unsigned)__builtin_amdgcn_cvt_pk_fp8_f32(e0, e1, 0, false);
  dw = (unsigned)__builtin_amdgcn_cvt_pk_fp8_f32(e2, e3, (int)dw, true);
  return dw;
#else
  return enc8(e0) | (enc8(e1) << 8) | (enc8(e2) << 16) | (enc8(e3) << 24);
#endif
}

// ---------------- NT GEMM core: C(128x128) = A[M,K] * B[N,K]^T, bf16 in, fp32 acc.
// 256 threads = 4 waves (2x2 of 64x64). K multiple of 32. BK=32.
__device__ __forceinline__ void gemm_core_nt(
    const unsigned short* __restrict__ A, long lda,
    const unsigned short* __restrict__ B, long ldb,
    int K, unsigned short* As, unsigned short* Bs, f32x4 acc[4][4])
{
  const int tid  = threadIdx.x;
  const int lane = tid & 63;
  const int w    = tid >> 6;
  const int wm   = w >> 1, wn = w & 1;
  const int r16  = lane & 15;
  const int kq   = lane >> 4;

  const int j0 = w * 64 + lane;         // slots 0..255   -> rows 0..63
  const int j1 = (w + 4) * 64 + lane;   // slots 256..511 -> rows 64..127
  const int r0 = j0 >> 2, cc0 = (((j0 & 3) - (r0 >> 1)) & 3);
  const int r1 = j1 >> 2, cc1 = (((j1 & 3) - (r1 >> 1)) & 3);

  const long a0 = (long)r0 * lda + cc0 * 8;
  const long a1 = (long)r1 * lda + cc1 * 8;
  const long b0 = (long)r0 * ldb + cc0 * 8;
  const long b1 = (long)r1 * ldb + cc1 * 8;

  int aoff[4], boff[4];
#pragma unroll
  for (int mt = 0; mt < 4; ++mt) {
    const int row = wm * 64 + mt * 16 + r16;
    aoff[mt] = row * 32 + (((row >> 1) + kq) & 3) * 8;
  }
#pragma unroll
  for (int nt = 0; nt < 4; ++nt) {
    const int row = wn * 64 + nt * 16 + r16;
    boff[nt] = row * 32 + (((row >> 1) + kq) & 3) * 8;
  }

  for (int k0 = 0; k0 < K; k0 += 32) {
    __syncthreads();
    async_copy16(A + a0 + k0, (char*)As + (w    ) * 1024);
    async_copy16(A + a1 + k0, (char*)As + (w + 4) * 1024);
    async_copy16(B + b0 + k0, (char*)Bs + (w    ) * 1024);
    async_copy16(B + b1 + k0, (char*)Bs + (w + 4) * 1024);
    __syncthreads();

    bf16x8 af[4], bg[4];
#pragma unroll
    for (int mt = 0; mt < 4; ++mt) af[mt] = *(const bf16x8*)&As[aoff[mt]];
#pragma unroll
    for (int nt = 0; nt < 4; ++nt) bg[nt] = *(const bf16x8*)&Bs[boff[nt]];
#pragma unroll
    for (int mt = 0; mt < 4; ++mt)
#pragma unroll
      for (int nt = 0; nt < 4; ++nt)
        acc[mt][nt] = __builtin_amdgcn_mfma_f32_16x16x32_bf16(af[mt], bg[nt], acc[mt][nt], 0, 0, 0);
  }
}

// ---------------- k_prep: all casts + zeroing in ONE launch
// blocks [0,16384): cast X; [16384,16896): cast Wq/Wk; [16896,17216): zero accums+out
__global__ __launch_bounds__(256) void k_prep(
    const float* __restrict__ X, const float* __restrict__ Wq, const float* __restrict__ Wk,
    unsigned short* __restrict__ Xbf, unsigned short* __restrict__ Wqb,
    unsigned short* __restrict__ Wkb, float* __restrict__ zp, float* __restrict__ out)
{
  const int blk = blockIdx.x;
  if (blk < 16384) {
    int i = (blk * 256 + threadIdx.x) * 4;
    float4 v = *(const float4*)(X + i);
    ushort4 o;
    o.x = f2bf(v.x); o.y = f2bf(v.y); o.z = f2bf(v.z); o.w = f2bf(v.w);
    *(ushort4*)(Xbf + i) = o;
  } else if (blk < 16896) {
    const int b2 = blk - 16384;
    const float* s = (b2 < 256) ? Wq : Wk;
    unsigned short* d = (b2 < 256) ? Wqb : Wkb;
    int i = ((b2 & 255) * 256 + threadIdx.x) * 4;
    float4 v = *(const float4*)(s + i);
    ushort4 o;
    o.x = f2bf(v.x); o.y = f2bf(v.y); o.z = f2bf(v.z); o.w = f2bf(v.w);
    *(ushort4*)(d + i) = o;
  } else {
    int i = (blk - 16896) * 256 + threadIdx.x;
    if (i < 73728) zp[i] = 0.0f;
    else out[i - 73728] = 0.0f;   // 73728+8192 = 81920 = 320*256 exactly
  }
}

// ---------------- k_mt: Mt[e,d] = scale * sum_c Wk[e,c] Wq[d,c], 64x64 tiles (grid 8x8)
__global__ __launch_bounds__(256) void k_mt(
    const unsigned short* __restrict__ A, const unsigned short* __restrict__ B,
    unsigned short* __restrict__ C, float scale)
{
  __shared__ alignas(16) unsigned short As[64 * 32];
  __shared__ alignas(16) unsigned short Bs[64 * 32];
  f32x4 acc[2][2] = {};
  const int tid = threadIdx.x, lane = tid & 63, w = tid >> 6;
  const int wm = w >> 1, wn = w & 1, r16 = lane & 15, kq = lane >> 4;
  const long a0row = (long)blockIdx.y * 64, b0row = (long)blockIdx.x * 64;

  // producer: thread tid handles chunk j=tid: row=j>>2, slot=j&3, src chunk (slot-row)&3
  const int prow = tid >> 2, pslot = tid & 3, pc = (pslot - prow) & 3;
  const long asrc = (a0row + prow) * 512 + pc * 8;
  const long bsrc = (b0row + prow) * 512 + pc * 8;

  int aoff[2], boff[2];
#pragma unroll
  for (int t = 0; t < 2; ++t) {
    const int m = wm * 32 + t * 16 + r16;
    aoff[t] = m * 32 + ((m + kq) & 3) * 8;
    const int n = wn * 32 + t * 16 + r16;
    boff[t] = n * 32 + ((n + kq) & 3) * 8;
  }

  for (int k0 = 0; k0 < 512; k0 += 32) {
    __syncthreads();
    async_copy16(A + asrc + k0, (char*)As + w * 1024);
    async_copy16(B + bsrc + k0, (char*)Bs + w * 1024);
    __syncthreads();
    bf16x8 af[2], bg[2];
#pragma unroll
    for (int t = 0; t < 2; ++t) { af[t] = *(const bf16x8*)&As[aoff[t]]; bg[t] = *(const bf16x8*)&Bs[boff[t]]; }
#pragma unroll
    for (int mt = 0; mt < 2; ++mt)
#pragma unroll
      for (int nt = 0; nt < 2; ++nt)
        acc[mt][nt] = __builtin_amdgcn_mfma_f32_16x16x32_bf16(af[mt], bg[nt], acc[mt][nt], 0, 0, 0);
  }

  const int quad = lane >> 4;
#pragma unroll
  for (int mt = 0; mt < 2; ++mt)
#pragma unroll
    for (int nt = 0; nt < 2; ++nt)
#pragma unroll
      for (int r = 0; r < 4; ++r)
        C[(a0row + wm * 32 + mt * 16 + quad * 4 + r) * 512 + b0row + wn * 32 + nt * 16 + r16]
            = f2bf(acc[mt][nt][r] * scale);
}

// ---------------- Y-GEMM with bf16 output (128x128 tiles)
__global__ __launch_bounds__(256) void k_gemm_bf16out(
    const unsigned short* __restrict__ A, long lda,
    const unsigned short* __restrict__ B, long ldb, int K,
    unsigned short* __restrict__ C, long ldc, float scale)
{
  __shared__ alignas(16) unsigned short As[128 * 32];
  __shared__ alignas(16) unsigned short Bs[128 * 32];
  f32x4 acc[4][4] = {};
  const long am0 = (long)blockIdx.y * 128;
  const long bn0 = (long)blockIdx.x * 128;
  gemm_core_nt(A + am0 * lda, lda, B + bn0 * ldb, ldb, K, As, Bs, acc);

  const int lane = threadIdx.x & 63;
  const int w = threadIdx.x >> 6, wm = w >> 1, wn = w & 1;
  const long row0 = am0 + wm * 64 + (lane >> 4) * 4;
  const long col0 = bn0 + wn * 64 + (lane & 15);
#pragma unroll
  for (int mt = 0; mt < 4; ++mt)
#pragma unroll
    for (int nt = 0; nt < 4; ++nt)
#pragma unroll
      for (int r = 0; r < 4; ++r)
        C[(row0 + mt * 16 + r) * ldc + col0 + nt * 16] = f2bf(acc[mt][nt][r] * scale);
}

// ---------------- pass A: scores -> exp2 -> row sums (atomic) + fp8 E (tiled)
union SMemAE {
  struct { unsigned short As[128 * 32]; unsigned short Bs[128 * 32]; } s;
  unsigned E32[128 * 36];   // [col][r4], stride-36 pad
};

__global__ __launch_bounds__(256) void k_passAE(
    const unsigned short* __restrict__ Ybf, const unsigned short* __restrict__ Xbf,
    float* __restrict__ lrow, unsigned* __restrict__ E)
{
  __shared__ SMemAE sm;
  f32x4 acc[4][4] = {};
  const int b = blockIdx.z, qt = blockIdx.y, kt = blockIdx.x;
  const long q0 = (long)qt * 128;
  const long n0 = (long)kt * 128;
  gemm_core_nt(Ybf + ((long)b * S_LEN + q0) * D_DIM, D_DIM,
               Xbf + ((long)b * S_LEN + n0) * D_DIM, D_DIM, D_DIM,
               sm.s.As, sm.s.Bs, acc);

  const int lane = threadIdx.x & 63;
  const int w = threadIdx.x >> 6, wm = w >> 1, wn = w & 1;
  const int r16 = lane & 15, quad = lane >> 4;

  __syncthreads();   // all waves' ds_reads done before As/Bs reused as E32

#pragma unroll
  for (int mt = 0; mt < 4; ++mt) {
    float rs[4] = {0.f, 0.f, 0.f, 0.f};
#pragma unroll
    for (int nt = 0; nt < 4; ++nt) {
      float ev[4];
#pragma unroll
      for (int r = 0; r < 4; ++r) {
        ev[r] = __builtin_amdgcn_exp2f(acc[mt][nt][r]);
        rs[r] += ev[r];
      }
      const int col = wn * 64 + nt * 16 + r16;
      const int r4  = wm * 16 + mt * 4 + quad;
      sm.E32[col * 36 + r4] = pack4_fp8(ev[0], ev[1], ev[2], ev[3]);
    }
#pragma unroll
    for (int r = 0; r < 4; ++r) {
      float s = rs[r];
      s += __shfl_xor(s, 1, 64);
      s += __shfl_xor(s, 2, 64);
      s += __shfl_xor(s, 4, 64);
      s += __shfl_xor(s, 8, 64);
      if (r16 == 0)
        atomicAdd(&lrow[(long)b * S_LEN + q0 + wm * 64 + mt * 16 + quad * 4 + r], s);
    }
  }
  __syncthreads();

  unsigned* Eg = E + (((long)(b * 16 + qt)) * 16 + kt) * 4096;
  const int t = threadIdx.x;
#pragma unroll
  for (int p = 0; p < 4; ++p) {
    const int n = p * 256 + t;            // uint4 index 0..1023
    const int col = n >> 3, hj = n & 7;
    uint4 v = *(const uint4*)&sm.E32[col * 36 + hj * 4];
    *(uint4*)(Eg + n * 4) = v;
  }
}

// ---------------- w[b,k] += sum_q E[b,q,k]/l[b,q]  (tiled-layout, coalesced)
__global__ __launch_bounds__(256) void k_wsum(
    const unsigned* __restrict__ E, const float* __restrict__ lrow,
    float* __restrict__ wcol)
{
  __shared__ float rl[512];
  const int kt = blockIdx.x, qq = blockIdx.y, b = blockIdx.z;
  const int tid = threadIdx.x;
  {
    const float* lp = lrow + (long)b * S_LEN + qq * 512;
    rl[tid]       = 1.0f / lp[tid];
    rl[tid + 256] = 1.0f / lp[tid + 256];
  }
  __syncthreads();
  const int col = tid & 127, qsel = tid >> 7;
  float acc = 0.0f;
#pragma unroll
  for (int qt2 = 0; qt2 < 2; ++qt2) {
    const int qtl = qsel * 2 + qt2;
    const int qt = qq * 4 + qtl;
    const unsigned* Ep = E + (((long)(b * 16 + qt)) * 16 + kt) * 4096 + col * 32;
    const float* rlq = rl + qtl * 128;
#pragma unroll
    for (int j = 0; j < 8; ++j) {
      uint4 v = *(const uint4*)(Ep + j * 4);
      const unsigned dws[4] = {v.x, v.y, v.z, v.w};
#pragma unroll
      for (int i = 0; i < 4; ++i) {
        const unsigned dv = dws[i];
        const float* r = rlq + j * 16 + i * 4;
#if HAVE_FP8CVT
        acc += __builtin_amdgcn_cvt_f32_fp8((int)dv, 0) * r[0];
        acc += __builtin_amdgcn_cvt_f32_fp8((int)dv, 1) * r[1];
        acc += __builtin_amdgcn_cvt_f32_fp8((int)dv, 2) * r[2];
        acc += __builtin_amdgcn_cvt_f32_fp8((int)dv, 3) * r[3];
#else
        acc += dec8( dv        & 0xFFu) * r[0];
        acc += dec8((dv >>  8) & 0xFFu) * r[1];
        acc += dec8((dv >> 16) & 0xFFu) * r[2];
        acc += dec8((dv >> 24)        ) * r[3];
#endif
      }
    }
  }
  atomicAdd(&wcol[(long)b * S_LEN + kt * 128 + col], acc);
}

// ---------------- fallback pass A/B (no E store; recompute) for small ws
__global__ __launch_bounds__(256) void k_passA(
    const unsigned short* __restrict__ Ybf, const unsigned short* __restrict__ Xbf,
    float* __restrict__ lrow)
{
  __shared__ alignas(16) unsigned short As[128 * 32];
  __shared__ alignas(16) unsigned short Bs[128 * 32];
  f32x4 acc[4][4] = {};
  const int b = blockIdx.z;
  const long q0 = (long)blockIdx.y * 128;
  const long n0 = (long)blockIdx.x * 128;
  gemm_core_nt(Ybf + ((long)b * S_LEN + q0) * D_DIM, D_DIM,
               Xbf + ((long)b * S_LEN + n0) * D_DIM, D_DIM, D_DIM, As, Bs, acc);

  const int lane = threadIdx.x & 63;
  const int w = threadIdx.x >> 6, wm = w >> 1;
#pragma unroll
  for (int mt = 0; mt < 4; ++mt) {
#pragma unroll
    for (int r = 0; r < 4; ++r) {
      float s = 0.0f;
#pragma unroll
      for (int nt = 0; nt < 4; ++nt) s += __builtin_amdgcn_exp2f(acc[mt][nt][r]);
      s += __shfl_xor(s, 1, 64);
      s += __shfl_xor(s, 2, 64);
      s += __shfl_xor(s, 4, 64);
      s += __shfl_xor(s, 8, 64);
      if ((lane & 15) == 0)
        atomicAdd(&lrow[(long)b * S_LEN + q0 + wm * 64 + mt * 16 + (lane >> 4) * 4 + r], s);
    }
  }
}

__global__ __launch_bounds__(256) void k_passB(
    const unsigned short* __restrict__ Ybf, const unsigned short* __restrict__ Xbf,
    const float* __restrict__ lrow, float* __restrict__ wcol)
{
  __shared__ alignas(16) unsigned short As[128 * 32];
  __shared__ alignas(16) unsigned short Bs[128 * 32];
  f32x4 acc[4][4] = {};
  const int b = blockIdx.z;
  const long q0 = (long)blockIdx.y * 128;
  const long n0 = (long)blockIdx.x * 128;
  gemm_core_nt(Ybf + ((long)b * S_LEN + q0) * D_DIM, D_DIM,
               Xbf + ((long)b * S_LEN + n0) * D_DIM, D_DIM, D_DIM, As, Bs, acc);

  const int lane = threadIdx.x & 63;
  const int w = threadIdx.x >> 6, wm = w >> 1, wn = w & 1;
  float csv[4] = {0.0f, 0.0f, 0.0f, 0.0f};
#pragma unroll
  for (int mt = 0; mt < 4; ++mt) {
    const float4 lv = *(const float4*)&lrow[(long)b * S_LEN + q0 + wm * 64 + mt * 16 + (lane >> 4) * 4];
    const float rv[4] = {1.0f / lv.x, 1.0f / lv.y, 1.0f / lv.z, 1.0f / lv.w};
#pragma unroll
    for (int nt = 0; nt < 4; ++nt)
#pragma unroll
      for (int r = 0; r < 4; ++r)
        csv[nt] += __builtin_amdgcn_exp2f(acc[mt][nt][r]) * rv[r];
  }
#pragma unroll
  for (int nt = 0; nt < 4; ++nt) {
    csv[nt] += __shfl_xor(csv[nt], 16, 64);
    csv[nt] += __shfl_xor(csv[nt], 32, 64);
  }
  if (lane < 16) {
#pragma unroll
    for (int nt = 0; nt < 4; ++nt)
      atomicAdd(&wcol[(long)b * S_LEN + n0 + wn * 64 + nt * 16 + lane], csv[nt]);
  }
}

// ---------------- t[b,d] = sum_k w[b,k] * X[b,k,d]  (bf16 X, k-split)
__global__ __launch_bounds__(256) void k_t(
    const unsigned short* __restrict__ Xbf, const float* __restrict__ wcol,
    float* __restrict__ tvec)
{
  const int b = blockIdx.z;
  const int d = blockIdx.x * 256 + threadIdx.x;
  const int k0 = blockIdx.y * 64;
  const unsigned short* Xp = Xbf + ((long)b * S_LEN + k0) * D_DIM + d;
  const float* wp = wcol + (long)b * S_LEN + k0;
  float acc = 0.0f;
#pragma unroll 8
  for (int k = 0; k < 64; ++k) acc += wp[k] * bf2f(Xp[(long)k * D_DIM]);
  atomicAdd(&tvec[b * D_DIM + d], acc);
}

// ---------------- out[b,e] += sum_{d chunk} t[b,d] * Wv[d,e]  (fp32, d-split)
__global__ __launch_bounds__(128) void k_out(
    const float* __restrict__ tvec, const float* __restrict__ Wv, float* __restrict__ out)
{
  __shared__ float tl[128];
  const int b = blockIdx.y;
  const int d0 = blockIdx.z * 128;
  const int e = blockIdx.x * 128 + threadIdx.x;
  tl[threadIdx.x] = tvec[b * D_DIM + d0 + threadIdx.x];
  __syncthreads();
  float acc = 0.0f;
#pragma unroll 8
  for (int d = 0; d < 128; ++d) acc += tl[d] * Wv[(long)(d0 + d) * D_DIM + e];
  atomicAdd(&out[b * D_DIM + e], acc);
}

extern "C" void kernel_launch(void* const* d_in, const int* in_sizes, int n_in,
                              void* d_out, int out_size, void* d_ws, size_t ws_size,
                              hipStream_t stream) {
  const float* X  = (const float*)d_in[0];  // [16,2048,512]
  const float* Wq = (const float*)d_in[1];  // [512,512]
  const float* Wk = (const float*)d_in[2];
  const float* Wv = (const float*)d_in[3];
  float* out = (float*)d_out;               // [16,512]

  char* ws = (char*)d_ws;
  unsigned short* Xbf = (unsigned short*)(ws);              // 32 MB
  unsigned short* Ybf = (unsigned short*)(ws + 33554432);   // 32 MB
  unsigned short* Mt  = (unsigned short*)(ws + 67108864);   // 512 KB (Mt[e,d] = M[d,e]*scale)
  unsigned short* Wqb = (unsigned short*)(ws + 67633152);   // 512 KB
  unsigned short* Wkb = (unsigned short*)(ws + 68157440);   // 512 KB
  float* lrow = (float*)(ws + 68681728);                    // 128 KB  l[b,q]
  float* wcol = (float*)(ws + 68812800);                    // 128 KB  w[b,k]
  float* tvec = (float*)(ws + 68943872);                    // 32 KB   t[b,d]
  unsigned* E = (unsigned*)(ws + 69206016);                 // 64 MB   fp8 E, tiled
  const bool bigws = ws_size >= (size_t)69206016 + (size_t)67108864;

  // one launch: cast X, cast Wq/Wk, zero lrow/wcol/tvec + out
  k_prep<<<17216, 256, 0, stream>>>(X, Wq, Wk, Xbf, Wqb, Wkb, lrow, out);

  // Mt[e,d] = (log2(e)/sqrt(512)) * sum_c Wk[e,c] Wq[d,c]  (64x64 tiles, 64 blocks)
  const float scale = 1.4426950408889634f / 22.627416997969522f;
  k_mt<<<dim3(8, 8), 256, 0, stream>>>(Wkb, Wqb, Mt, scale);

  // Y[i,e] = sum_d Xbf[i,d] * Mt[e,d]
  k_gemm_bf16out<<<dim3(4, 256), 256, 0, stream>>>(Xbf, 512, Mt, 512, 512, Ybf, 512, 1.0f);

  if (bigws) {
    k_passAE<<<dim3(16, 16, 16), 256, 0, stream>>>(Ybf, Xbf, lrow, E);
    k_wsum<<<dim3(16, 4, 16), 256, 0, stream>>>(E, lrow, wcol);
  } else {
    k_passA<<<dim3(16, 16, 16), 256, 0, stream>>>(Ybf, Xbf, lrow);
    k_passB<<<dim3(16, 16, 16), 256, 0, stream>>>(Ybf, Xbf, lrow, wcol);
  }

  // t = w @ X (bf16 X), out = t @ Wv (fp32)
  k_t<<<dim3(2, 32, 16), 256, 0, stream>>>(Xbf, wcol, tvec);
  k_out<<<dim3(4, 16, 4), 128, 0, stream>>>(tvec, Wv, out);
}